// Round 13
// baseline (226.592 us; speedup 1.0000x reference)
//
#include <hip/hip_runtime.h>
#include <hip/hip_bf16.h>

static constexpr int B = 8;
static constexpr int C = 384;
static constexpr int H = 32;
static constexpr int W = 32;
static constexpr int N = 1024;      // H*W
static constexpr int Cg = 128;      // C/G
static constexpr int HEADS = 12;
static constexpr int BG = 24;      // B*G
static constexpr float SCALE = 0.17677669529663687f; // hc^-0.5
static constexpr float LOG2E = 1.4426950408889634f;

typedef short bf16x8 __attribute__((ext_vector_type(8)));
typedef float f32x4 __attribute__((ext_vector_type(4)));

__device__ __forceinline__ unsigned short bf16_bits(float x) {
    __hip_bfloat16 h = __float2bfloat16(x);
    return __builtin_bit_cast(unsigned short, h);
}
__device__ __forceinline__ float bf2f(unsigned short u) {
    return __builtin_bit_cast(float, ((unsigned)u) << 16);
}
__device__ __forceinline__ float fast_tanh(float x) {
    float e = __expf(2.0f * x);
    return 1.0f - 2.0f / (e + 1.0f);
}

// ---------------------------------------------------------------------------
// prep: blocks 0..287 convert 4 weight matrices to bf16 (one-time);
// blocks 288..1055 transpose x1 fp32 -> bf16 token-major [b][1024][384].
// ---------------------------------------------------------------------------
__global__ __launch_bounds__(256) void prep(const float* __restrict__ wq,
                                            const float* __restrict__ wk,
                                            const float* __restrict__ wv,
                                            const float* __restrict__ wo,
                                            const float* __restrict__ x1,
                                            unsigned short* __restrict__ w16,
                                            unsigned short* __restrict__ x1T)
{
    __shared__ float tile[32][132];
    const int bx = blockIdx.x;
    const int tid = threadIdx.x;
    if (bx < 288) {
        int which = bx / 72, blk = bx - which*72;
        const float* src = (which == 0) ? wq : (which == 1) ? wk : (which == 2) ? wv : wo;
        int idx = (blk*256 + tid) * 8;
        const float4* p = (const float4*)(src + idx);
        float4 f0 = p[0], f1 = p[1];
        uint4 u;
        u.x = (unsigned)bf16_bits(f0.x) | ((unsigned)bf16_bits(f0.y) << 16);
        u.y = (unsigned)bf16_bits(f0.z) | ((unsigned)bf16_bits(f0.w) << 16);
        u.z = (unsigned)bf16_bits(f1.x) | ((unsigned)bf16_bits(f1.y) << 16);
        u.w = (unsigned)bf16_bits(f1.z) | ((unsigned)bf16_bits(f1.w) << 16);
        *(uint4*)(w16 + (size_t)which * 147456 + idx) = u;
        return;
    }
    const int xi = bx - 288;
    const int n0 = (xi & 7) * 128;
    const int t = xi >> 3;               // 0..95
    const int c0 = (t % 12) * 32;
    const int b = t / 12;
    {
        int c = tid >> 3, nq = (tid & 7) * 16;
        const float* sp = x1 + ((size_t)b*C + c0 + c)*N + n0 + nq;
        #pragma unroll
        for (int i = 0; i < 4; ++i)
            *(float4*)&tile[c][nq + 4*i] = *(const float4*)(sp + 4*i);
    }
    __syncthreads();
    {
        int n = tid >> 1, cb = (tid & 1) * 16;
        unsigned short* dp = x1T + ((size_t)b*N + n0 + n)*C + c0 + cb;
        #pragma unroll
        for (int half = 0; half < 2; ++half) {
            bf16x8 v;
            #pragma unroll
            for (int j = 0; j < 8; ++j)
                v[j] = (short)bf16_bits(tile[cb + half*8 + j][n]);
            *(bf16x8*)(dp + half*8) = v;
        }
    }
}

// ---------------------------------------------------------------------------
// MFMA projection: acc[n][o] = sum_c XT[n][c] * Wb[o][c]; bf16 weights.
// MODE 2: out fp32 spatial + bias + residual
// MODE 3: out bf16 token-major + bias  AND bf16 spatial + bias
// ---------------------------------------------------------------------------
template<int MODE>
__global__ __launch_bounds__(256) void proj_mfma(const unsigned short* __restrict__ XT,
                                                 const unsigned short* __restrict__ Wb,
                                                 const float* __restrict__ bias,
                                                 const float* __restrict__ res,
                                                 void* __restrict__ out,
                                                 void* __restrict__ out2)
{
    __shared__ __align__(16) char smem[64*72*2*2];   // 18,432 B
    unsigned short* sA = (unsigned short*)smem;      // [64n][72c]
    unsigned short* sB = sA + 64*72;                 // [64o][72c]
    float* ep = (float*)smem;                        // epilogue [64n][65o]

    const int tid = threadIdx.x;
    const int lane = tid & 63, w = tid >> 6;
    const int l15 = lane & 15, lq = lane >> 4;
    const int n0 = blockIdx.x * 64, o0 = blockIdx.y * 64, b = blockIdx.z;
    const int qn = (w & 1) * 32, qo = (w >> 1) * 32;

    const unsigned short* xg = XT + ((size_t)b*N + n0)*C;
    const unsigned short* wg = Wb + (size_t)o0*C;

    const f32x4 zero = {0.f, 0.f, 0.f, 0.f};
    f32x4 a00 = zero, a01 = zero, a10 = zero, a11 = zero;

    const int r = tid >> 2, c8 = (tid & 3) * 8;
    for (int c0 = 0; c0 < C; c0 += 64) {
        __syncthreads();
        *(bf16x8*)(sA + r*72 + c8)      = *(const bf16x8*)(xg + (size_t)r*C + c0 + c8);
        *(bf16x8*)(sA + r*72 + c8 + 32) = *(const bf16x8*)(xg + (size_t)r*C + c0 + c8 + 32);
        *(bf16x8*)(sB + r*72 + c8)      = *(const bf16x8*)(wg + (size_t)r*C + c0 + c8);
        *(bf16x8*)(sB + r*72 + c8 + 32) = *(const bf16x8*)(wg + (size_t)r*C + c0 + c8 + 32);
        __syncthreads();
        #pragma unroll
        for (int ks = 0; ks < 2; ++ks) {
            bf16x8 fa0 = *(const bf16x8*)(sA + (qn + l15)*72      + ks*32 + lq*8);
            bf16x8 fa1 = *(const bf16x8*)(sA + (qn + 16 + l15)*72 + ks*32 + lq*8);
            bf16x8 fb0 = *(const bf16x8*)(sB + (qo + l15)*72      + ks*32 + lq*8);
            bf16x8 fb1 = *(const bf16x8*)(sB + (qo + 16 + l15)*72 + ks*32 + lq*8);
            a00 = __builtin_amdgcn_mfma_f32_16x16x32_bf16(fa0, fb0, a00, 0, 0, 0);
            a01 = __builtin_amdgcn_mfma_f32_16x16x32_bf16(fa0, fb1, a01, 0, 0, 0);
            a10 = __builtin_amdgcn_mfma_f32_16x16x32_bf16(fa1, fb0, a10, 0, 0, 0);
            a11 = __builtin_amdgcn_mfma_f32_16x16x32_bf16(fa1, fb1, a11, 0, 0, 0);
        }
    }
    __syncthreads();
    #pragma unroll
    for (int rr = 0; rr < 4; ++rr) {
        int nr0 = qn + 4*lq + rr, nr1 = qn + 16 + 4*lq + rr;
        ep[nr0*65 + qo + l15]      = a00[rr];
        ep[nr0*65 + qo + 16 + l15] = a01[rr];
        ep[nr1*65 + qo + l15]      = a10[rr];
        ep[nr1*65 + qo + 16 + l15] = a11[rr];
    }
    __syncthreads();

    if constexpr (MODE == 3) {
        {   // token-major bf16
            int n = tid >> 2, ch = tid & 3;
            unsigned short* op = (unsigned short*)out + ((size_t)b*N + n0 + n)*C + o0;
            #pragma unroll
            for (int half = 0; half < 2; ++half) {
                int ob = ch*8 + half*32;
                bf16x8 v;
                #pragma unroll
                for (int j = 0; j < 8; ++j)
                    v[j] = (short)bf16_bits(ep[n*65 + ob + j] + bias[o0 + ob + j]);
                *(bf16x8*)(op + ob) = v;
            }
        }
        {   // bf16 spatial (for dwconv)
            int o = tid >> 2, nc = (tid & 3) * 16;
            float bz = bias[o0 + o];
            unsigned short* dp = (unsigned short*)out2 + ((size_t)b*C + o0 + o)*N + n0 + nc;
            #pragma unroll
            for (int half = 0; half < 2; ++half) {
                bf16x8 v;
                #pragma unroll
                for (int j = 0; j < 8; ++j)
                    v[j] = (short)bf16_bits(ep[(nc + half*8 + j)*65 + o] + bz);
                *(bf16x8*)(dp + half*8) = v;
            }
        }
    } else {
        int o = tid >> 2, nc = (tid & 3) * 16;
        float bz = bias[o0 + o];
        size_t base = ((size_t)b*C + o0 + o)*N + n0 + nc;
        #pragma unroll
        for (int i = 0; i < 4; ++i) {
            float4 rv = *(const float4*)(res + base + 4*i);
            f32x4 v;
            v[0] = ep[(nc + 4*i + 0)*65 + o] + bz + rv.x;
            v[1] = ep[(nc + 4*i + 1)*65 + o] + bz + rv.y;
            v[2] = ep[(nc + 4*i + 2)*65 + o] + bz + rv.z;
            v[3] = ep[(nc + 4*i + 3)*65 + o] + bz + rv.w;
            __builtin_nontemporal_store(v, (f32x4*)((float*)out + base + 4*i));
        }
    }
}

// ---------------------------------------------------------------------------
// Fused K+V projection (bf16 weights). One sampT staging, two outputs.
// K scaled by SCALE*LOG2E so attention can use raw exp2.
// ---------------------------------------------------------------------------
__global__ __launch_bounds__(256) void proj_kv(const unsigned short* __restrict__ XT,
                                               const unsigned short* __restrict__ Wk,
                                               const float* __restrict__ bk,
                                               const unsigned short* __restrict__ Wv,
                                               const float* __restrict__ bv,
                                               unsigned short* __restrict__ K16,
                                               unsigned short* __restrict__ V16)
{
    __shared__ __align__(16) char smem[64*72*2*3];   // 27,648 B
    unsigned short* sA  = (unsigned short*)smem;
    unsigned short* sBk = sA + 64*72;
    unsigned short* sBv = sA + 2*64*72;
    float* ep = (float*)smem;                        // [64n][65o]

    const int tid = threadIdx.x;
    const int lane = tid & 63, w = tid >> 6;
    const int l15 = lane & 15, lq = lane >> 4;
    const int n0 = blockIdx.x * 64, o0 = blockIdx.y * 64, b = blockIdx.z;
    const int qn = (w & 1) * 32, qo = (w >> 1) * 32;

    const unsigned short* xg = XT + ((size_t)b*N + n0)*C;
    const unsigned short* wkg = Wk + (size_t)o0*C;
    const unsigned short* wvg = Wv + (size_t)o0*C;

    const f32x4 zero = {0.f, 0.f, 0.f, 0.f};
    f32x4 k00 = zero, k01 = zero, k10 = zero, k11 = zero;
    f32x4 v00 = zero, v01 = zero, v10 = zero, v11 = zero;

    const int r = tid >> 2, c8 = (tid & 3) * 8;
    for (int c0 = 0; c0 < C; c0 += 64) {
        __syncthreads();
        *(bf16x8*)(sA  + r*72 + c8)      = *(const bf16x8*)(xg  + (size_t)r*C + c0 + c8);
        *(bf16x8*)(sA  + r*72 + c8 + 32) = *(const bf16x8*)(xg  + (size_t)r*C + c0 + c8 + 32);
        *(bf16x8*)(sBk + r*72 + c8)      = *(const bf16x8*)(wkg + (size_t)r*C + c0 + c8);
        *(bf16x8*)(sBk + r*72 + c8 + 32) = *(const bf16x8*)(wkg + (size_t)r*C + c0 + c8 + 32);
        *(bf16x8*)(sBv + r*72 + c8)      = *(const bf16x8*)(wvg + (size_t)r*C + c0 + c8);
        *(bf16x8*)(sBv + r*72 + c8 + 32) = *(const bf16x8*)(wvg + (size_t)r*C + c0 + c8 + 32);
        __syncthreads();
        #pragma unroll
        for (int ks = 0; ks < 2; ++ks) {
            bf16x8 fa0 = *(const bf16x8*)(sA + (qn + l15)*72      + ks*32 + lq*8);
            bf16x8 fa1 = *(const bf16x8*)(sA + (qn + 16 + l15)*72 + ks*32 + lq*8);
            bf16x8 fk0 = *(const bf16x8*)(sBk + (qo + l15)*72      + ks*32 + lq*8);
            bf16x8 fk1 = *(const bf16x8*)(sBk + (qo + 16 + l15)*72 + ks*32 + lq*8);
            bf16x8 fv0 = *(const bf16x8*)(sBv + (qo + l15)*72      + ks*32 + lq*8);
            bf16x8 fv1 = *(const bf16x8*)(sBv + (qo + 16 + l15)*72 + ks*32 + lq*8);
            k00 = __builtin_amdgcn_mfma_f32_16x16x32_bf16(fa0, fk0, k00, 0, 0, 0);
            k01 = __builtin_amdgcn_mfma_f32_16x16x32_bf16(fa0, fk1, k01, 0, 0, 0);
            k10 = __builtin_amdgcn_mfma_f32_16x16x32_bf16(fa1, fk0, k10, 0, 0, 0);
            k11 = __builtin_amdgcn_mfma_f32_16x16x32_bf16(fa1, fk1, k11, 0, 0, 0);
            v00 = __builtin_amdgcn_mfma_f32_16x16x32_bf16(fa0, fv0, v00, 0, 0, 0);
            v01 = __builtin_amdgcn_mfma_f32_16x16x32_bf16(fa0, fv1, v01, 0, 0, 0);
            v10 = __builtin_amdgcn_mfma_f32_16x16x32_bf16(fa1, fv0, v10, 0, 0, 0);
            v11 = __builtin_amdgcn_mfma_f32_16x16x32_bf16(fa1, fv1, v11, 0, 0, 0);
        }
    }
    // ---- K epilogue (token-major bf16, *SCALE*LOG2E) ----
    __syncthreads();
    #pragma unroll
    for (int rr = 0; rr < 4; ++rr) {
        int nr0 = qn + 4*lq + rr, nr1 = qn + 16 + 4*lq + rr;
        ep[nr0*65 + qo + l15]      = k00[rr];
        ep[nr0*65 + qo + 16 + l15] = k01[rr];
        ep[nr1*65 + qo + l15]      = k10[rr];
        ep[nr1*65 + qo + 16 + l15] = k11[rr];
    }
    __syncthreads();
    {
        int n = tid >> 2, ch = tid & 3;
        unsigned short* op = K16 + ((size_t)b*N + n0 + n)*C + o0;
        #pragma unroll
        for (int half = 0; half < 2; ++half) {
            int ob = ch*8 + half*32;
            bf16x8 v;
            #pragma unroll
            for (int j = 0; j < 8; ++j)
                v[j] = (short)bf16_bits((ep[n*65 + ob + j] + bk[o0 + ob + j]) * (SCALE * LOG2E));
            *(bf16x8*)(op + ob) = v;
        }
    }
    // ---- V epilogue (spatial bf16) ----
    __syncthreads();
    #pragma unroll
    for (int rr = 0; rr < 4; ++rr) {
        int nr0 = qn + 4*lq + rr, nr1 = qn + 16 + 4*lq + rr;
        ep[nr0*65 + qo + l15]      = v00[rr];
        ep[nr0*65 + qo + 16 + l15] = v01[rr];
        ep[nr1*65 + qo + l15]      = v10[rr];
        ep[nr1*65 + qo + 16 + l15] = v11[rr];
    }
    __syncthreads();
    {
        int o = tid >> 2, nc = (tid & 3) * 16;
        float bz = bv[o0 + o];
        unsigned short* op = V16 + ((size_t)b*C + o0 + o)*N + n0 + nc;
        #pragma unroll
        for (int half = 0; half < 2; ++half) {
            bf16x8 v;
            #pragma unroll
            for (int j = 0; j < 8; ++j)
                v[j] = (short)bf16_bits(ep[(nc + half*8 + j)*65 + o] + bz);
            *(bf16x8*)(op + half*8) = v;
        }
    }
}

// ---------------------------------------------------------------------------
// Depthwise 5x5 conv (SAME, zero-pad) + bias + tanh GELU, halo-tiled in LDS.
// bf16 in, bf16 out. grid (4, 128, 24)
// ---------------------------------------------------------------------------
__global__ __launch_bounds__(256) void dwconv_gelu(const unsigned short* __restrict__ q,
                                                   const float* __restrict__ wdw,
                                                   const float* __restrict__ bdw,
                                                   unsigned short* __restrict__ t)
{
    __shared__ float tile[12][32];
    __shared__ float wsm[25];
    const int bx = blockIdx.x;           // 0..3 (8-row stripes)
    const int c = blockIdx.y, bg = blockIdx.z;
    const int tid = threadIdx.x;
    const unsigned short* qc = q + ((size_t)bg*Cg + c)*N;
    if (tid < 384) {
        int row = tid >> 5, col = tid & 31;
        int gy = bx*8 - 2 + row;
        tile[row][col] = (gy >= 0 && gy < H) ? bf2f(qc[gy*W + col]) : 0.0f;
    }
    if (tid < 25) wsm[tid] = wdw[c*25 + tid];
    __syncthreads();
    const int yl = tid >> 5, x = tid & 31;
    float acc = bdw[c];
    #pragma unroll
    for (int ky = 0; ky < 5; ++ky) {
        #pragma unroll
        for (int kx = 0; kx < 5; ++kx) {
            int xx = x + kx - 2;
            if (xx < 0 || xx >= W) continue;
            acc += wsm[ky*5 + kx] * tile[yl + ky][xx];
        }
    }
    float u = acc;
    float g = 0.5f*u*(1.0f + fast_tanh(0.7978845608028654f*(u + 0.044715f*u*u*u)));
    t[((size_t)bg*Cg + c)*N + bx*256 + tid] = bf16_bits(g);
}

// ---------------------------------------------------------------------------
// Merged: pointwise conv(2) + tanh + grid + bilinear gather -> sampT bf16.
// Reads bf16 tbuf. grid (16, 24)
// ---------------------------------------------------------------------------
__global__ __launch_bounds__(256) void offbilin(const unsigned short* __restrict__ t,
                                                const float* __restrict__ wpw,
                                                const float* __restrict__ bpw,
                                                const float* __restrict__ x2,
                                                unsigned short* __restrict__ sampT)
{
    __shared__ float r0[4][64], r1[4][64];
    __shared__ float4 cbuf[64];
    __shared__ unsigned short st[64][130];
    const int tid = threadIdx.x;
    const int n0 = blockIdx.x * 64, bg = blockIdx.y;
    const int nl = tid & 63, cq = tid >> 6;
    {
        const unsigned short* tb = t + ((size_t)bg*Cg + cq*32)*N + n0 + nl;
        float a0 = 0.f, a1 = 0.f;
        #pragma unroll 8
        for (int i = 0; i < 32; ++i) {
            float tv = bf2f(tb[(size_t)i*N]);
            a0 += wpw[cq*32 + i] * tv;
            a1 += wpw[Cg + cq*32 + i] * tv;
        }
        r0[cq][nl] = a0; r1[cq][nl] = a1;
    }
    __syncthreads();
    if (tid < 64) {
        int n = n0 + nl;
        const int x = n & 31, y = n >> 5;
        float a0 = bpw[0] + r0[0][nl] + r0[1][nl] + r0[2][nl] + r0[3][nl];
        float a1 = bpw[1] + r1[0][nl] + r1[1][nl] + r1[2][nl] + r1[3][nl];
        float dx = fast_tanh(a0) * (2.0f / W);
        float dy = fast_tanh(a1) * (2.0f / H);
        float rx = (x + 0.5f) / W * 2.0f - 1.0f;
        float ry = (y + 0.5f) / H * 2.0f - 1.0f;
        float px = fminf(fmaxf(rx + dx, -1.0f), 1.0f);
        float py = fminf(fmaxf(ry + dy, -1.0f), 1.0f);
        float gx = (px + 1.0f) * 0.5f * (W - 1);
        float gy = (py + 1.0f) * 0.5f * (H - 1);
        float x0 = floorf(gx), y0 = floorf(gy);
        float wx1 = gx - x0, wy1 = gy - y0;
        x0 = fminf(fmaxf(x0, 0.0f), (float)(W - 1));
        y0 = fminf(fmaxf(y0, 0.0f), (float)(H - 1));
        cbuf[nl] = make_float4(x0, y0, wx1, wy1);
    }
    __syncthreads();
    {
        float4 c4 = cbuf[nl];
        int x0 = (int)c4.x, y0 = (int)c4.y;
        float wx1 = c4.z, wy1 = c4.w;
        int x1 = min(x0 + 1, W - 1), y1 = min(y0 + 1, H - 1);
        float wx0 = 1.0f - wx1, wy0 = 1.0f - wy1;
        const float* base = x2 + (size_t)bg*Cg*N;
        #pragma unroll 4
        for (int i = 0; i < 32; ++i) {
            int c = cq*32 + i;
            const float* img = base + (size_t)c*N;
            float v00 = img[y0*W + x0], v01 = img[y0*W + x1];
            float v10 = img[y1*W + x0], v11 = img[y1*W + x1];
            float v = wy0*(wx0*v00 + wx1*v01) + wy1*(wx0*v10 + wx1*v11);
            st[nl][c] = bf16_bits(v);
        }
    }
    __syncthreads();
    {
        int b = bg / 3, g = bg % 3;
        int nn = tid >> 2;
        unsigned short* dp = sampT + ((size_t)b*N + n0 + nn)*C + g*Cg;
        #pragma unroll
        for (int i = 0; i < 4; ++i) {
            int c8 = ((tid & 3) + 4*i) * 8;
            *(bf16x8*)(dp + c8) = *(const bf16x8*)&st[nn][c8];
        }
    }
}

// ---------------------------------------------------------------------------
// Fused attention v7: BARRIER-FREE. K/V fragments read directly from global
// (each K row = exactly one 64B line; V rows fully consumed over the loop —
// zero waste, L2-resident via XCD swizzle). LDS = per-wave P tile only
// (9.2 KB). 2-pass, exp2 (K pre-scaled by log2e), transposed NT stores.
// grid (1536), 256 threads.
// ---------------------------------------------------------------------------
__global__ __launch_bounds__(256) void attn_fused(const unsigned short* __restrict__ Q16,
                                                  const unsigned short* __restrict__ K16,
                                                  const unsigned short* __restrict__ V16,
                                                  float* __restrict__ attn,
                                                  unsigned short* __restrict__ OT)
{
    __shared__ __align__(16) unsigned short ps[4][16*72];  // 9,216 B total

    const int tid = threadIdx.x;
    const int lane = tid & 63, w = tid >> 6;
    const int l15 = lane & 15, lq = lane >> 4;
    const int id = blockIdx.x;
    const int xcd = id & 7, j = id >> 3;
    const int bh = xcd*12 + (j >> 4);
    const int nb = j & 15;
    const int b = bh / HEADS, h = bh - b*HEADS;

    const unsigned short* qg = Q16 + ((size_t)b*N + nb*64)*C + h*32;
    const unsigned short* kg = K16 + (size_t)b*N*C + h*32;
    const unsigned short* vg = V16 + ((size_t)b*C + h*32)*N;

    const bf16x8 qfrag = *(const bf16x8*)(qg + (size_t)(w*16 + l15)*C + lq*8);

    const f32x4 zero = {0.f, 0.f, 0.f, 0.f};
    float sm = 0.f;
    f32x4 s[16];

    // ---------------- PASS 1: row sums (K direct from global/L2) -----------
    for (int ch = 0; ch < 4; ++ch) {
        #pragma unroll
        for (int t = 0; t < 16; ++t) {
            bf16x8 kfrag = *(const bf16x8*)(kg + (size_t)(ch*256 + 16*t + l15)*C + lq*8);
            s[t] = __builtin_amdgcn_mfma_f32_16x16x32_bf16(kfrag, qfrag, zero, 0, 0, 0);
        }
        float es = 0.f;
        #pragma unroll
        for (int t = 0; t < 16; ++t) {
            es += exp2f(s[t][0]); es += exp2f(s[t][1]);
            es += exp2f(s[t][2]); es += exp2f(s[t][3]);
        }
        sm += es;
    }
    sm += __shfl_xor(sm, 16);
    sm += __shfl_xor(sm, 32);
    const float inv = 1.0f / sm;

    // ---------------- PASS 2: recompute + P write + PV ----------------
    f32x4 outf[2] = {zero, zero};
    unsigned short* pw = ps[w];
    float* abase = attn + ((size_t)bh*N + (size_t)nb*64 + w*16)*N;
    const int trow = lane >> 4;
    const int tcol = (lane & 15) * 4;

    for (int ch = 0; ch < 4; ++ch) {
        #pragma unroll
        for (int t = 0; t < 16; ++t) {
            bf16x8 kfrag = *(const bf16x8*)(kg + (size_t)(ch*256 + 16*t + l15)*C + lq*8);
            s[t] = __builtin_amdgcn_mfma_f32_16x16x32_bf16(kfrag, qfrag, zero, 0, 0, 0);
        }
        #pragma unroll
        for (int qr = 0; qr < 4; ++qr) {
            #pragma unroll
            for (int tt = 0; tt < 4; ++tt) {
                int t = qr*4 + tt;
                float e0 = exp2f(s[t][0]), e1 = exp2f(s[t][1]);
                float e2 = exp2f(s[t][2]), e3 = exp2f(s[t][3]);
                uint2 pb;
                pb.x = (unsigned)bf16_bits(e0) | ((unsigned)bf16_bits(e1) << 16);
                pb.y = (unsigned)bf16_bits(e2) | ((unsigned)bf16_bits(e3) << 16);
                *(uint2*)(pw + l15*72 + 16*tt + 4*lq) = pb;
            }
            __asm volatile("" ::: "memory");
            // PV MFMAs: V fragments direct from global/L2
            #pragma unroll
            for (int kk = 0; kk < 2; ++kk) {
                bf16x8 pa = *(const bf16x8*)(pw + l15*72 + kk*32 + lq*8);
                #pragma unroll
                for (int ct = 0; ct < 2; ++ct) {
                    bf16x8 vb = *(const bf16x8*)(vg + (size_t)(16*ct + l15)*N
                                                 + ch*256 + qr*64 + kk*32 + lq*8);
                    outf[ct] = __builtin_amdgcn_mfma_f32_16x16x32_bf16(pa, vb, outf[ct], 0, 0, 0);
                }
            }
            // transposed attn store: 4 rows x 256B per instruction
            #pragma unroll
            for (int it = 0; it < 4; ++it) {
                int row = it*4 + trow;
                uint2 u = *(const uint2*)(pw + row*72 + tcol);
                float invr = __shfl(inv, row);
                f32x4 p;
                p[0] = __builtin_bit_cast(float, u.x << 16) * invr;
                p[1] = __builtin_bit_cast(float, u.x & 0xffff0000u) * invr;
                p[2] = __builtin_bit_cast(float, u.y << 16) * invr;
                p[3] = __builtin_bit_cast(float, u.y & 0xffff0000u) * invr;
                __builtin_nontemporal_store(p,
                    (f32x4*)(abase + (size_t)row*N + ch*256 + qr*64 + tcol));
            }
            __asm volatile("" ::: "memory");
        }
    }

    // epilogue: fold inv (per output row n = 4lq+r) into PV result
    float* sc = (float*)pw;   // [16n][33c]
    #pragma unroll
    for (int r = 0; r < 4; ++r) {
        float invr = __shfl(inv, 4*lq + r);
        sc[(4*lq + r)*33 + l15]      = outf[0][r] * invr;
        sc[(4*lq + r)*33 + 16 + l15] = outf[1][r] * invr;
    }
    __asm volatile("" ::: "memory");
    {
        int n = lane >> 2, c8 = (lane & 3) * 8;
        bf16x8 v;
        #pragma unroll
        for (int j2 = 0; j2 < 8; ++j2)
            v[j2] = (short)bf16_bits(sc[n*33 + c8 + j2]);
        *(bf16x8*)(OT + ((size_t)b*N + nb*64 + w*16 + n)*C + h*32 + c8) = v;
    }
}

// ---------------------------------------------------------------------------
extern "C" void kernel_launch(void* const* d_in, const int* in_sizes, int n_in,
                              void* d_out, int out_size, void* d_ws, size_t ws_size,
                              hipStream_t stream)
{
    const float* x1  = (const float*)d_in[0];
    const float* x2  = (const float*)d_in[1];
    const float* wq  = (const float*)d_in[2];
    const float* bq  = (const float*)d_in[3];
    const float* wdw = (const float*)d_in[4];
    const float* bdw = (const float*)d_in[5];
    const float* wpw = (const float*)d_in[6];
    const float* bpw = (const float*)d_in[7];
    const float* wk  = (const float*)d_in[8];
    const float* bk  = (const float*)d_in[9];
    const float* wv  = (const float*)d_in[10];
    const float* bv  = (const float*)d_in[11];
    const float* wo  = (const float*)d_in[12];
    const float* bo  = (const float*)d_in[13];

    const size_t P = (size_t)B * C * N;          // 3,145,728 floats
    float* ws = (float*)d_ws;
    unsigned short* Q16   = (unsigned short*)ws;             // P ushorts
    unsigned short* qspat = (unsigned short*)(ws + P/2);     // P ushorts (bf16 spatial)
    unsigned short* sampT = (unsigned short*)(ws + P);       // P ushorts
    unsigned short* K16   = (unsigned short*)(ws + 3*P/2);   // P ushorts
    unsigned short* V16   = (unsigned short*)(ws + 2*P);     // P ushorts
    unsigned short* x1T   = (unsigned short*)(ws + 5*P/2);   // P ushorts, reused as OT
    unsigned short* OT    = x1T;
    unsigned short* tbuf  = (unsigned short*)(ws + 3*P);     // P ushorts (bf16)
    unsigned short* w16   = (unsigned short*)(ws + 7*P/2);   // 4*147456 halves
    unsigned short* w16q = w16;
    unsigned short* w16k = w16 + 147456;
    unsigned short* w16v = w16 + 2*147456;
    unsigned short* w16o = w16 + 3*147456;

    float* ybuf = (float*)d_out;                 // (B,C,H,W)
    float* attn = (float*)d_out + P;             // (B,HEADS,N,N)

    prep<<<dim3(1056), 256, 0, stream>>>(wq, wk, wv, wo, x1, w16, x1T);
    proj_mfma<3><<<dim3(16, 6, 8), 256, 0, stream>>>(x1T, w16q, bq, nullptr, Q16, qspat);
    dwconv_gelu<<<dim3(4, Cg, BG), 256, 0, stream>>>(qspat, wdw, bdw, tbuf);
    offbilin<<<dim3(16, BG), 256, 0, stream>>>(tbuf, wpw, bpw, x2, sampT);
    proj_kv<<<dim3(16, 6, 8), 256, 0, stream>>>(sampT, w16k, bk, w16v, bv, K16, V16);
    attn_fused<<<dim3(1536), 256, 0, stream>>>(Q16, K16, V16, attn, OT);
    proj_mfma<2><<<dim3(16, 6, 8), 256, 0, stream>>>(OT, w16o, bo, x1, ybuf, nullptr);
}

// Round 14
// 174.535 us; speedup vs baseline: 1.2983x; 1.2983x over previous
//
#include <hip/hip_runtime.h>
#include <hip/hip_bf16.h>

static constexpr int B = 8;
static constexpr int C = 384;
static constexpr int H = 32;
static constexpr int W = 32;
static constexpr int N = 1024;      // H*W
static constexpr int Cg = 128;      // C/G
static constexpr int HEADS = 12;
static constexpr int BG = 24;      // B*G
static constexpr float SCALE = 0.17677669529663687f; // hc^-0.5
static constexpr float LOG2E = 1.4426950408889634f;

typedef short bf16x8 __attribute__((ext_vector_type(8)));
typedef float f32x4 __attribute__((ext_vector_type(4)));

__device__ __forceinline__ unsigned short bf16_bits(float x) {
    __hip_bfloat16 h = __float2bfloat16(x);
    return __builtin_bit_cast(unsigned short, h);
}
__device__ __forceinline__ float bf2f(unsigned short u) {
    return __builtin_bit_cast(float, ((unsigned)u) << 16);
}
__device__ __forceinline__ float fast_tanh(float x) {
    float e = __expf(2.0f * x);
    return 1.0f - 2.0f / (e + 1.0f);
}

// ---------------------------------------------------------------------------
// prep: blocks 0..287 convert 4 weight matrices to bf16 (one-time);
// blocks 288..1055 transpose x1 fp32 -> bf16 token-major [b][1024][384].
// ---------------------------------------------------------------------------
__global__ __launch_bounds__(256) void prep(const float* __restrict__ wq,
                                            const float* __restrict__ wk,
                                            const float* __restrict__ wv,
                                            const float* __restrict__ wo,
                                            const float* __restrict__ x1,
                                            unsigned short* __restrict__ w16,
                                            unsigned short* __restrict__ x1T)
{
    __shared__ float tile[32][132];
    const int bx = blockIdx.x;
    const int tid = threadIdx.x;
    if (bx < 288) {
        int which = bx / 72, blk = bx - which*72;
        const float* src = (which == 0) ? wq : (which == 1) ? wk : (which == 2) ? wv : wo;
        int idx = (blk*256 + tid) * 8;
        const float4* p = (const float4*)(src + idx);
        float4 f0 = p[0], f1 = p[1];
        uint4 u;
        u.x = (unsigned)bf16_bits(f0.x) | ((unsigned)bf16_bits(f0.y) << 16);
        u.y = (unsigned)bf16_bits(f0.z) | ((unsigned)bf16_bits(f0.w) << 16);
        u.z = (unsigned)bf16_bits(f1.x) | ((unsigned)bf16_bits(f1.y) << 16);
        u.w = (unsigned)bf16_bits(f1.z) | ((unsigned)bf16_bits(f1.w) << 16);
        *(uint4*)(w16 + (size_t)which * 147456 + idx) = u;
        return;
    }
    const int xi = bx - 288;
    const int n0 = (xi & 7) * 128;
    const int t = xi >> 3;               // 0..95
    const int c0 = (t % 12) * 32;
    const int b = t / 12;
    {
        int c = tid >> 3, nq = (tid & 7) * 16;
        const float* sp = x1 + ((size_t)b*C + c0 + c)*N + n0 + nq;
        #pragma unroll
        for (int i = 0; i < 4; ++i)
            *(float4*)&tile[c][nq + 4*i] = *(const float4*)(sp + 4*i);
    }
    __syncthreads();
    {
        int n = tid >> 1, cb = (tid & 1) * 16;
        unsigned short* dp = x1T + ((size_t)b*N + n0 + n)*C + c0 + cb;
        #pragma unroll
        for (int half = 0; half < 2; ++half) {
            bf16x8 v;
            #pragma unroll
            for (int j = 0; j < 8; ++j)
                v[j] = (short)bf16_bits(tile[cb + half*8 + j][n]);
            *(bf16x8*)(dp + half*8) = v;
        }
    }
}

// ---------------------------------------------------------------------------
// MFMA projection: acc[n][o] = sum_c XT[n][c] * Wb[o][c]; bf16 weights.
// MODE 2: out fp32 spatial + bias + residual
// MODE 3: out bf16 token-major + bias  AND bf16 spatial + bias
// ---------------------------------------------------------------------------
template<int MODE>
__global__ __launch_bounds__(256) void proj_mfma(const unsigned short* __restrict__ XT,
                                                 const unsigned short* __restrict__ Wb,
                                                 const float* __restrict__ bias,
                                                 const float* __restrict__ res,
                                                 void* __restrict__ out,
                                                 void* __restrict__ out2)
{
    __shared__ __align__(16) char smem[64*72*2*2];   // 18,432 B
    unsigned short* sA = (unsigned short*)smem;      // [64n][72c]
    unsigned short* sB = sA + 64*72;                 // [64o][72c]
    float* ep = (float*)smem;                        // epilogue [64n][65o]

    const int tid = threadIdx.x;
    const int lane = tid & 63, w = tid >> 6;
    const int l15 = lane & 15, lq = lane >> 4;
    const int n0 = blockIdx.x * 64, o0 = blockIdx.y * 64, b = blockIdx.z;
    const int qn = (w & 1) * 32, qo = (w >> 1) * 32;

    const unsigned short* xg = XT + ((size_t)b*N + n0)*C;
    const unsigned short* wg = Wb + (size_t)o0*C;

    const f32x4 zero = {0.f, 0.f, 0.f, 0.f};
    f32x4 a00 = zero, a01 = zero, a10 = zero, a11 = zero;

    const int r = tid >> 2, c8 = (tid & 3) * 8;
    for (int c0 = 0; c0 < C; c0 += 64) {
        __syncthreads();
        *(bf16x8*)(sA + r*72 + c8)      = *(const bf16x8*)(xg + (size_t)r*C + c0 + c8);
        *(bf16x8*)(sA + r*72 + c8 + 32) = *(const bf16x8*)(xg + (size_t)r*C + c0 + c8 + 32);
        *(bf16x8*)(sB + r*72 + c8)      = *(const bf16x8*)(wg + (size_t)r*C + c0 + c8);
        *(bf16x8*)(sB + r*72 + c8 + 32) = *(const bf16x8*)(wg + (size_t)r*C + c0 + c8 + 32);
        __syncthreads();
        #pragma unroll
        for (int ks = 0; ks < 2; ++ks) {
            bf16x8 fa0 = *(const bf16x8*)(sA + (qn + l15)*72      + ks*32 + lq*8);
            bf16x8 fa1 = *(const bf16x8*)(sA + (qn + 16 + l15)*72 + ks*32 + lq*8);
            bf16x8 fb0 = *(const bf16x8*)(sB + (qo + l15)*72      + ks*32 + lq*8);
            bf16x8 fb1 = *(const bf16x8*)(sB + (qo + 16 + l15)*72 + ks*32 + lq*8);
            a00 = __builtin_amdgcn_mfma_f32_16x16x32_bf16(fa0, fb0, a00, 0, 0, 0);
            a01 = __builtin_amdgcn_mfma_f32_16x16x32_bf16(fa0, fb1, a01, 0, 0, 0);
            a10 = __builtin_amdgcn_mfma_f32_16x16x32_bf16(fa1, fb0, a10, 0, 0, 0);
            a11 = __builtin_amdgcn_mfma_f32_16x16x32_bf16(fa1, fb1, a11, 0, 0, 0);
        }
    }
    __syncthreads();
    #pragma unroll
    for (int rr = 0; rr < 4; ++rr) {
        int nr0 = qn + 4*lq + rr, nr1 = qn + 16 + 4*lq + rr;
        ep[nr0*65 + qo + l15]      = a00[rr];
        ep[nr0*65 + qo + 16 + l15] = a01[rr];
        ep[nr1*65 + qo + l15]      = a10[rr];
        ep[nr1*65 + qo + 16 + l15] = a11[rr];
    }
    __syncthreads();

    if constexpr (MODE == 3) {
        {   // token-major bf16
            int n = tid >> 2, ch = tid & 3;
            unsigned short* op = (unsigned short*)out + ((size_t)b*N + n0 + n)*C + o0;
            #pragma unroll
            for (int half = 0; half < 2; ++half) {
                int ob = ch*8 + half*32;
                bf16x8 v;
                #pragma unroll
                for (int j = 0; j < 8; ++j)
                    v[j] = (short)bf16_bits(ep[n*65 + ob + j] + bias[o0 + ob + j]);
                *(bf16x8*)(op + ob) = v;
            }
        }
        {   // bf16 spatial (for dwconv)
            int o = tid >> 2, nc = (tid & 3) * 16;
            float bz = bias[o0 + o];
            unsigned short* dp = (unsigned short*)out2 + ((size_t)b*C + o0 + o)*N + n0 + nc;
            #pragma unroll
            for (int half = 0; half < 2; ++half) {
                bf16x8 v;
                #pragma unroll
                for (int j = 0; j < 8; ++j)
                    v[j] = (short)bf16_bits(ep[(nc + half*8 + j)*65 + o] + bz);
                *(bf16x8*)(dp + half*8) = v;
            }
        }
    } else {
        int o = tid >> 2, nc = (tid & 3) * 16;
        float bz = bias[o0 + o];
        size_t base = ((size_t)b*C + o0 + o)*N + n0 + nc;
        #pragma unroll
        for (int i = 0; i < 4; ++i) {
            float4 rv = *(const float4*)(res + base + 4*i);
            f32x4 v;
            v[0] = ep[(nc + 4*i + 0)*65 + o] + bz + rv.x;
            v[1] = ep[(nc + 4*i + 1)*65 + o] + bz + rv.y;
            v[2] = ep[(nc + 4*i + 2)*65 + o] + bz + rv.z;
            v[3] = ep[(nc + 4*i + 3)*65 + o] + bz + rv.w;
            __builtin_nontemporal_store(v, (f32x4*)((float*)out + base + 4*i));
        }
    }
}

// ---------------------------------------------------------------------------
// Fused K+V projection (bf16 weights). One sampT staging, two outputs.
// K scaled by SCALE*LOG2E so attention can use raw exp2.
// ---------------------------------------------------------------------------
__global__ __launch_bounds__(256) void proj_kv(const unsigned short* __restrict__ XT,
                                               const unsigned short* __restrict__ Wk,
                                               const float* __restrict__ bk,
                                               const unsigned short* __restrict__ Wv,
                                               const float* __restrict__ bv,
                                               unsigned short* __restrict__ K16,
                                               unsigned short* __restrict__ V16)
{
    __shared__ __align__(16) char smem[64*72*2*3];   // 27,648 B
    unsigned short* sA  = (unsigned short*)smem;
    unsigned short* sBk = sA + 64*72;
    unsigned short* sBv = sA + 2*64*72;
    float* ep = (float*)smem;                        // [64n][65o]

    const int tid = threadIdx.x;
    const int lane = tid & 63, w = tid >> 6;
    const int l15 = lane & 15, lq = lane >> 4;
    const int n0 = blockIdx.x * 64, o0 = blockIdx.y * 64, b = blockIdx.z;
    const int qn = (w & 1) * 32, qo = (w >> 1) * 32;

    const unsigned short* xg = XT + ((size_t)b*N + n0)*C;
    const unsigned short* wkg = Wk + (size_t)o0*C;
    const unsigned short* wvg = Wv + (size_t)o0*C;

    const f32x4 zero = {0.f, 0.f, 0.f, 0.f};
    f32x4 k00 = zero, k01 = zero, k10 = zero, k11 = zero;
    f32x4 v00 = zero, v01 = zero, v10 = zero, v11 = zero;

    const int r = tid >> 2, c8 = (tid & 3) * 8;
    for (int c0 = 0; c0 < C; c0 += 64) {
        __syncthreads();
        *(bf16x8*)(sA  + r*72 + c8)      = *(const bf16x8*)(xg  + (size_t)r*C + c0 + c8);
        *(bf16x8*)(sA  + r*72 + c8 + 32) = *(const bf16x8*)(xg  + (size_t)r*C + c0 + c8 + 32);
        *(bf16x8*)(sBk + r*72 + c8)      = *(const bf16x8*)(wkg + (size_t)r*C + c0 + c8);
        *(bf16x8*)(sBk + r*72 + c8 + 32) = *(const bf16x8*)(wkg + (size_t)r*C + c0 + c8 + 32);
        *(bf16x8*)(sBv + r*72 + c8)      = *(const bf16x8*)(wvg + (size_t)r*C + c0 + c8);
        *(bf16x8*)(sBv + r*72 + c8 + 32) = *(const bf16x8*)(wvg + (size_t)r*C + c0 + c8 + 32);
        __syncthreads();
        #pragma unroll
        for (int ks = 0; ks < 2; ++ks) {
            bf16x8 fa0 = *(const bf16x8*)(sA + (qn + l15)*72      + ks*32 + lq*8);
            bf16x8 fa1 = *(const bf16x8*)(sA + (qn + 16 + l15)*72 + ks*32 + lq*8);
            bf16x8 fk0 = *(const bf16x8*)(sBk + (qo + l15)*72      + ks*32 + lq*8);
            bf16x8 fk1 = *(const bf16x8*)(sBk + (qo + 16 + l15)*72 + ks*32 + lq*8);
            bf16x8 fv0 = *(const bf16x8*)(sBv + (qo + l15)*72      + ks*32 + lq*8);
            bf16x8 fv1 = *(const bf16x8*)(sBv + (qo + 16 + l15)*72 + ks*32 + lq*8);
            k00 = __builtin_amdgcn_mfma_f32_16x16x32_bf16(fa0, fk0, k00, 0, 0, 0);
            k01 = __builtin_amdgcn_mfma_f32_16x16x32_bf16(fa0, fk1, k01, 0, 0, 0);
            k10 = __builtin_amdgcn_mfma_f32_16x16x32_bf16(fa1, fk0, k10, 0, 0, 0);
            k11 = __builtin_amdgcn_mfma_f32_16x16x32_bf16(fa1, fk1, k11, 0, 0, 0);
            v00 = __builtin_amdgcn_mfma_f32_16x16x32_bf16(fa0, fv0, v00, 0, 0, 0);
            v01 = __builtin_amdgcn_mfma_f32_16x16x32_bf16(fa0, fv1, v01, 0, 0, 0);
            v10 = __builtin_amdgcn_mfma_f32_16x16x32_bf16(fa1, fv0, v10, 0, 0, 0);
            v11 = __builtin_amdgcn_mfma_f32_16x16x32_bf16(fa1, fv1, v11, 0, 0, 0);
        }
    }
    // ---- K epilogue (token-major bf16, *SCALE*LOG2E) ----
    __syncthreads();
    #pragma unroll
    for (int rr = 0; rr < 4; ++rr) {
        int nr0 = qn + 4*lq + rr, nr1 = qn + 16 + 4*lq + rr;
        ep[nr0*65 + qo + l15]      = k00[rr];
        ep[nr0*65 + qo + 16 + l15] = k01[rr];
        ep[nr1*65 + qo + l15]      = k10[rr];
        ep[nr1*65 + qo + 16 + l15] = k11[rr];
    }
    __syncthreads();
    {
        int n = tid >> 2, ch = tid & 3;
        unsigned short* op = K16 + ((size_t)b*N + n0 + n)*C + o0;
        #pragma unroll
        for (int half = 0; half < 2; ++half) {
            int ob = ch*8 + half*32;
            bf16x8 v;
            #pragma unroll
            for (int j = 0; j < 8; ++j)
                v[j] = (short)bf16_bits((ep[n*65 + ob + j] + bk[o0 + ob + j]) * (SCALE * LOG2E));
            *(bf16x8*)(op + ob) = v;
        }
    }
    // ---- V epilogue (spatial bf16) ----
    __syncthreads();
    #pragma unroll
    for (int rr = 0; rr < 4; ++rr) {
        int nr0 = qn + 4*lq + rr, nr1 = qn + 16 + 4*lq + rr;
        ep[nr0*65 + qo + l15]      = v00[rr];
        ep[nr0*65 + qo + 16 + l15] = v01[rr];
        ep[nr1*65 + qo + l15]      = v10[rr];
        ep[nr1*65 + qo + 16 + l15] = v11[rr];
    }
    __syncthreads();
    {
        int o = tid >> 2, nc = (tid & 3) * 16;
        float bz = bv[o0 + o];
        unsigned short* op = V16 + ((size_t)b*C + o0 + o)*N + n0 + nc;
        #pragma unroll
        for (int half = 0; half < 2; ++half) {
            bf16x8 v;
            #pragma unroll
            for (int j = 0; j < 8; ++j)
                v[j] = (short)bf16_bits(ep[(nc + half*8 + j)*65 + o] + bz);
            *(bf16x8*)(op + half*8) = v;
        }
    }
}

// ---------------------------------------------------------------------------
// Depthwise 5x5 conv (SAME, zero-pad) + bias + tanh GELU, halo-tiled in LDS.
// bf16 in, bf16 out. grid (4, 128, 24)
// ---------------------------------------------------------------------------
__global__ __launch_bounds__(256) void dwconv_gelu(const unsigned short* __restrict__ q,
                                                   const float* __restrict__ wdw,
                                                   const float* __restrict__ bdw,
                                                   unsigned short* __restrict__ t)
{
    __shared__ float tile[12][32];
    __shared__ float wsm[25];
    const int bx = blockIdx.x;           // 0..3 (8-row stripes)
    const int c = blockIdx.y, bg = blockIdx.z;
    const int tid = threadIdx.x;
    const unsigned short* qc = q + ((size_t)bg*Cg + c)*N;
    if (tid < 384) {
        int row = tid >> 5, col = tid & 31;
        int gy = bx*8 - 2 + row;
        tile[row][col] = (gy >= 0 && gy < H) ? bf2f(qc[gy*W + col]) : 0.0f;
    }
    if (tid < 25) wsm[tid] = wdw[c*25 + tid];
    __syncthreads();
    const int yl = tid >> 5, x = tid & 31;
    float acc = bdw[c];
    #pragma unroll
    for (int ky = 0; ky < 5; ++ky) {
        #pragma unroll
        for (int kx = 0; kx < 5; ++kx) {
            int xx = x + kx - 2;
            if (xx < 0 || xx >= W) continue;
            acc += wsm[ky*5 + kx] * tile[yl + ky][xx];
        }
    }
    float u = acc;
    float g = 0.5f*u*(1.0f + fast_tanh(0.7978845608028654f*(u + 0.044715f*u*u*u)));
    t[((size_t)bg*Cg + c)*N + bx*256 + tid] = bf16_bits(g);
}

// ---------------------------------------------------------------------------
// Merged: pointwise conv(2) + tanh + grid + bilinear gather -> sampT bf16.
// Reads bf16 tbuf. grid (16, 24)
// ---------------------------------------------------------------------------
__global__ __launch_bounds__(256) void offbilin(const unsigned short* __restrict__ t,
                                                const float* __restrict__ wpw,
                                                const float* __restrict__ bpw,
                                                const float* __restrict__ x2,
                                                unsigned short* __restrict__ sampT)
{
    __shared__ float r0[4][64], r1[4][64];
    __shared__ float4 cbuf[64];
    __shared__ unsigned short st[64][130];
    const int tid = threadIdx.x;
    const int n0 = blockIdx.x * 64, bg = blockIdx.y;
    const int nl = tid & 63, cq = tid >> 6;
    {
        const unsigned short* tb = t + ((size_t)bg*Cg + cq*32)*N + n0 + nl;
        float a0 = 0.f, a1 = 0.f;
        #pragma unroll 8
        for (int i = 0; i < 32; ++i) {
            float tv = bf2f(tb[(size_t)i*N]);
            a0 += wpw[cq*32 + i] * tv;
            a1 += wpw[Cg + cq*32 + i] * tv;
        }
        r0[cq][nl] = a0; r1[cq][nl] = a1;
    }
    __syncthreads();
    if (tid < 64) {
        int n = n0 + nl;
        const int x = n & 31, y = n >> 5;
        float a0 = bpw[0] + r0[0][nl] + r0[1][nl] + r0[2][nl] + r0[3][nl];
        float a1 = bpw[1] + r1[0][nl] + r1[1][nl] + r1[2][nl] + r1[3][nl];
        float dx = fast_tanh(a0) * (2.0f / W);
        float dy = fast_tanh(a1) * (2.0f / H);
        float rx = (x + 0.5f) / W * 2.0f - 1.0f;
        float ry = (y + 0.5f) / H * 2.0f - 1.0f;
        float px = fminf(fmaxf(rx + dx, -1.0f), 1.0f);
        float py = fminf(fmaxf(ry + dy, -1.0f), 1.0f);
        float gx = (px + 1.0f) * 0.5f * (W - 1);
        float gy = (py + 1.0f) * 0.5f * (H - 1);
        float x0 = floorf(gx), y0 = floorf(gy);
        float wx1 = gx - x0, wy1 = gy - y0;
        x0 = fminf(fmaxf(x0, 0.0f), (float)(W - 1));
        y0 = fminf(fmaxf(y0, 0.0f), (float)(H - 1));
        cbuf[nl] = make_float4(x0, y0, wx1, wy1);
    }
    __syncthreads();
    {
        float4 c4 = cbuf[nl];
        int x0 = (int)c4.x, y0 = (int)c4.y;
        float wx1 = c4.z, wy1 = c4.w;
        int x1 = min(x0 + 1, W - 1), y1 = min(y0 + 1, H - 1);
        float wx0 = 1.0f - wx1, wy0 = 1.0f - wy1;
        const float* base = x2 + (size_t)bg*Cg*N;
        #pragma unroll 4
        for (int i = 0; i < 32; ++i) {
            int c = cq*32 + i;
            const float* img = base + (size_t)c*N;
            float v00 = img[y0*W + x0], v01 = img[y0*W + x1];
            float v10 = img[y1*W + x0], v11 = img[y1*W + x1];
            float v = wy0*(wx0*v00 + wx1*v01) + wy1*(wx0*v10 + wx1*v11);
            st[nl][c] = bf16_bits(v);
        }
    }
    __syncthreads();
    {
        int b = bg / 3, g = bg % 3;
        int nn = tid >> 2;
        unsigned short* dp = sampT + ((size_t)b*N + n0 + nn)*C + g*Cg;
        #pragma unroll
        for (int i = 0; i < 4; ++i) {
            int c8 = ((tid & 3) + 4*i) * 8;
            *(bf16x8*)(dp + c8) = *(const bf16x8*)&st[nn][c8];
        }
    }
}

// ---------------------------------------------------------------------------
// Fused attention v6' (R12 structure + exp2): 2-pass, LDS-staged K/V,
// transposed row-contiguous NT attn stores. LDS 46.6KB -> 3 blocks/CU.
// grid (1536), XCD-chunked swizzle.
// ---------------------------------------------------------------------------
__global__ __launch_bounds__(256) void attn_fused(const unsigned short* __restrict__ Q16,
                                                  const unsigned short* __restrict__ K16,
                                                  const unsigned short* __restrict__ V16,
                                                  float* __restrict__ attn,
                                                  unsigned short* __restrict__ OT)
{
    __shared__ __align__(16) unsigned short ks[256*40];    // 20,480 B
    __shared__ __align__(16) unsigned short vs[32*264];    // 16,896 B
    __shared__ __align__(16) unsigned short ps[4][16*72];  //  9,216 B

    const int tid = threadIdx.x;
    const int lane = tid & 63, w = tid >> 6;
    const int l15 = lane & 15, lq = lane >> 4;
    const int id = blockIdx.x;
    const int xcd = id & 7, j = id >> 3;
    const int bh = xcd*12 + (j >> 4);
    const int nb = j & 15;
    const int b = bh / HEADS, h = bh - b*HEADS;

    const unsigned short* qg = Q16 + ((size_t)b*N + nb*64)*C + h*32;
    const unsigned short* kg = K16 + (size_t)b*N*C + h*32;
    const unsigned short* vg = V16 + ((size_t)b*C + h*32)*N;

    const bf16x8 qfrag = *(const bf16x8*)(qg + (size_t)(w*16 + l15)*C + lq*8);

    const f32x4 zero = {0.f, 0.f, 0.f, 0.f};
    float sm = 0.f;
    f32x4 s[16];

    // ---------------- PASS 1: row sums only ----------------
    for (int ch = 0; ch < 4; ++ch) {
        __syncthreads();
        #pragma unroll
        for (int i = 0; i < 4; ++i) {
            int m = i*64 + (tid >> 2), c8 = (tid & 3) * 8;
            *(bf16x8*)(ks + m*40 + c8) = *(const bf16x8*)(kg + ((size_t)ch*256 + m)*C + c8);
        }
        __syncthreads();
        #pragma unroll
        for (int t = 0; t < 16; ++t) {
            bf16x8 kfrag = *(const bf16x8*)(ks + (16*t + l15)*40 + lq*8);
            s[t] = __builtin_amdgcn_mfma_f32_16x16x32_bf16(kfrag, qfrag, zero, 0, 0, 0);
        }
        float es = 0.f;
        #pragma unroll
        for (int t = 0; t < 16; ++t) {
            es += exp2f(s[t][0]); es += exp2f(s[t][1]);
            es += exp2f(s[t][2]); es += exp2f(s[t][3]);
        }
        sm += es;
    }
    sm += __shfl_xor(sm, 16);
    sm += __shfl_xor(sm, 32);
    const float inv = 1.0f / sm;

    // ---------------- PASS 2: recompute + P write + PV ----------------
    f32x4 outf[2] = {zero, zero};
    unsigned short* pw = ps[w];
    float* abase = attn + ((size_t)bh*N + (size_t)nb*64 + w*16)*N;
    const int trow = lane >> 4;
    const int tcol = (lane & 15) * 4;

    for (int ch = 0; ch < 4; ++ch) {
        __syncthreads();
        #pragma unroll
        for (int i = 0; i < 4; ++i) {
            int m = i*64 + (tid >> 2), c8 = (tid & 3) * 8;
            *(bf16x8*)(ks + m*40 + c8) = *(const bf16x8*)(kg + ((size_t)ch*256 + m)*C + c8);
        }
        #pragma unroll
        for (int i = 0; i < 4; ++i) {
            int u = tid + i*256;
            int cl = u >> 5, gg = u & 31;
            *(bf16x8*)(vs + cl*264 + gg*8) = *(const bf16x8*)(vg + (size_t)cl*N + ch*256 + gg*8);
        }
        __syncthreads();
        #pragma unroll
        for (int t = 0; t < 16; ++t) {
            bf16x8 kfrag = *(const bf16x8*)(ks + (16*t + l15)*40 + lq*8);
            s[t] = __builtin_amdgcn_mfma_f32_16x16x32_bf16(kfrag, qfrag, zero, 0, 0, 0);
        }
        #pragma unroll
        for (int qr = 0; qr < 4; ++qr) {
            #pragma unroll
            for (int tt = 0; tt < 4; ++tt) {
                int t = qr*4 + tt;
                float e0 = exp2f(s[t][0]), e1 = exp2f(s[t][1]);
                float e2 = exp2f(s[t][2]), e3 = exp2f(s[t][3]);
                uint2 pb;
                pb.x = (unsigned)bf16_bits(e0) | ((unsigned)bf16_bits(e1) << 16);
                pb.y = (unsigned)bf16_bits(e2) | ((unsigned)bf16_bits(e3) << 16);
                *(uint2*)(pw + l15*72 + 16*tt + 4*lq) = pb;
            }
            __asm volatile("" ::: "memory");
            #pragma unroll
            for (int kk = 0; kk < 2; ++kk) {
                bf16x8 pa = *(const bf16x8*)(pw + l15*72 + kk*32 + lq*8);
                #pragma unroll
                for (int ct = 0; ct < 2; ++ct) {
                    bf16x8 vb = *(const bf16x8*)(vs + (16*ct + l15)*264 + qr*64 + kk*32 + lq*8);
                    outf[ct] = __builtin_amdgcn_mfma_f32_16x16x32_bf16(pa, vb, outf[ct], 0, 0, 0);
                }
            }
            #pragma unroll
            for (int it = 0; it < 4; ++it) {
                int row = it*4 + trow;
                uint2 u = *(const uint2*)(pw + row*72 + tcol);
                float invr = __shfl(inv, row);
                f32x4 p;
                p[0] = __builtin_bit_cast(float, u.x << 16) * invr;
                p[1] = __builtin_bit_cast(float, u.x & 0xffff0000u) * invr;
                p[2] = __builtin_bit_cast(float, u.y << 16) * invr;
                p[3] = __builtin_bit_cast(float, u.y & 0xffff0000u) * invr;
                __builtin_nontemporal_store(p,
                    (f32x4*)(abase + (size_t)row*N + ch*256 + qr*64 + tcol));
            }
            __asm volatile("" ::: "memory");
        }
    }

    // epilogue: fold inv (per output row n = 4lq+r) into PV result
    float* sc = (float*)pw;   // [16n][33c]
    #pragma unroll
    for (int r = 0; r < 4; ++r) {
        float invr = __shfl(inv, 4*lq + r);
        sc[(4*lq + r)*33 + l15]      = outf[0][r] * invr;
        sc[(4*lq + r)*33 + 16 + l15] = outf[1][r] * invr;
    }
    __asm volatile("" ::: "memory");
    {
        int n = lane >> 2, c8 = (lane & 3) * 8;
        bf16x8 v;
        #pragma unroll
        for (int j2 = 0; j2 < 8; ++j2)
            v[j2] = (short)bf16_bits(sc[n*33 + c8 + j2]);
        *(bf16x8*)(OT + ((size_t)b*N + nb*64 + w*16 + n)*C + h*32 + c8) = v;
    }
}

// ---------------------------------------------------------------------------
extern "C" void kernel_launch(void* const* d_in, const int* in_sizes, int n_in,
                              void* d_out, int out_size, void* d_ws, size_t ws_size,
                              hipStream_t stream)
{
    const float* x1  = (const float*)d_in[0];
    const float* x2  = (const float*)d_in[1];
    const float* wq  = (const float*)d_in[2];
    const float* bq  = (const float*)d_in[3];
    const float* wdw = (const float*)d_in[4];
    const float* bdw = (const float*)d_in[5];
    const float* wpw = (const float*)d_in[6];
    const float* bpw = (const float*)d_in[7];
    const float* wk  = (const float*)d_in[8];
    const float* bk  = (const float*)d_in[9];
    const float* wv  = (const float*)d_in[10];
    const float* bv  = (const float*)d_in[11];
    const float* wo  = (const float*)d_in[12];
    const float* bo  = (const float*)d_in[13];

    const size_t P = (size_t)B * C * N;          // 3,145,728 floats
    float* ws = (float*)d_ws;
    unsigned short* Q16   = (unsigned short*)ws;             // P ushorts
    unsigned short* qspat = (unsigned short*)(ws + P/2);     // P ushorts (bf16 spatial)
    unsigned short* sampT = (unsigned short*)(ws + P);       // P ushorts
    unsigned short* K16   = (unsigned short*)(ws + 3*P/2);   // P ushorts
    unsigned short* V16   = (unsigned short*)(ws + 2*P);     // P ushorts
    unsigned short* x1T   = (unsigned short*)(ws + 5*P/2);   // P ushorts, reused as OT
    unsigned short* OT    = x1T;
    unsigned short* tbuf  = (unsigned short*)(ws + 3*P);     // P ushorts (bf16)
    unsigned short* w16   = (unsigned short*)(ws + 7*P/2);   // 4*147456 halves
    unsigned short* w16q = w16;
    unsigned short* w16k = w16 + 147456;
    unsigned short* w16v = w16 + 2*147456;
    unsigned short* w16o = w16 + 3*147456;

    float* ybuf = (float*)d_out;                 // (B,C,H,W)
    float* attn = (float*)d_out + P;             // (B,HEADS,N,N)

    prep<<<dim3(1056), 256, 0, stream>>>(wq, wk, wv, wo, x1, w16, x1T);
    proj_mfma<3><<<dim3(16, 6, 8), 256, 0, stream>>>(x1T, w16q, bq, nullptr, Q16, qspat);
    dwconv_gelu<<<dim3(4, Cg, BG), 256, 0, stream>>>(qspat, wdw, bdw, tbuf);
    offbilin<<<dim3(16, BG), 256, 0, stream>>>(tbuf, wpw, bpw, x2, sampT);
    proj_kv<<<dim3(16, 6, 8), 256, 0, stream>>>(sampT, w16k, bk, w16v, bv, K16, V16);
    attn_fused<<<dim3(1536), 256, 0, stream>>>(Q16, K16, V16, attn, OT);
    proj_mfma<2><<<dim3(16, 6, 8), 256, 0, stream>>>(OT, w16o, bo, x1, ybuf, nullptr);
}

// Round 15
// 168.702 us; speedup vs baseline: 1.3432x; 1.0346x over previous
//
#include <hip/hip_runtime.h>
#include <hip/hip_bf16.h>

static constexpr int B = 8;
static constexpr int C = 384;
static constexpr int H = 32;
static constexpr int W = 32;
static constexpr int N = 1024;      // H*W
static constexpr int Cg = 128;      // C/G
static constexpr int HEADS = 12;
static constexpr int BG = 24;      // B*G
static constexpr float SCALE = 0.17677669529663687f; // hc^-0.5
static constexpr float LOG2E = 1.4426950408889634f;

// Fast exp selection: raw v_exp_f32 (exp2) if the builtin exists, else __expf.
// K projection scale must match: exp2 path needs log2e folded into K.
#if defined(__has_builtin)
#if __has_builtin(__builtin_amdgcn_exp2f)
#define USE_EXP2 1
#endif
#endif
#ifdef USE_EXP2
#define KSCALE (SCALE * LOG2E)
__device__ __forceinline__ float fexp(float x) { return __builtin_amdgcn_exp2f(x); }
#else
#define KSCALE (SCALE)
__device__ __forceinline__ float fexp(float x) { return __expf(x); }
#endif

typedef short bf16x8 __attribute__((ext_vector_type(8)));
typedef float f32x4 __attribute__((ext_vector_type(4)));

__device__ __forceinline__ unsigned short bf16_bits(float x) {
    __hip_bfloat16 h = __float2bfloat16(x);
    return __builtin_bit_cast(unsigned short, h);
}
__device__ __forceinline__ float bf2f(unsigned short u) {
    return __builtin_bit_cast(float, ((unsigned)u) << 16);
}
__device__ __forceinline__ float fast_tanh(float x) {
    float e = __expf(2.0f * x);
    return 1.0f - 2.0f / (e + 1.0f);
}

// ---------------------------------------------------------------------------
// prep: blocks 0..287 convert 4 weight matrices to bf16 (one-time);
// blocks 288..1055 transpose x1 fp32 -> bf16 token-major [b][1024][384].
// ---------------------------------------------------------------------------
__global__ __launch_bounds__(256) void prep(const float* __restrict__ wq,
                                            const float* __restrict__ wk,
                                            const float* __restrict__ wv,
                                            const float* __restrict__ wo,
                                            const float* __restrict__ x1,
                                            unsigned short* __restrict__ w16,
                                            unsigned short* __restrict__ x1T)
{
    __shared__ float tile[32][132];
    const int bx = blockIdx.x;
    const int tid = threadIdx.x;
    if (bx < 288) {
        int which = bx / 72, blk = bx - which*72;
        const float* src = (which == 0) ? wq : (which == 1) ? wk : (which == 2) ? wv : wo;
        int idx = (blk*256 + tid) * 8;
        const float4* p = (const float4*)(src + idx);
        float4 f0 = p[0], f1 = p[1];
        uint4 u;
        u.x = (unsigned)bf16_bits(f0.x) | ((unsigned)bf16_bits(f0.y) << 16);
        u.y = (unsigned)bf16_bits(f0.z) | ((unsigned)bf16_bits(f0.w) << 16);
        u.z = (unsigned)bf16_bits(f1.x) | ((unsigned)bf16_bits(f1.y) << 16);
        u.w = (unsigned)bf16_bits(f1.z) | ((unsigned)bf16_bits(f1.w) << 16);
        *(uint4*)(w16 + (size_t)which * 147456 + idx) = u;
        return;
    }
    const int xi = bx - 288;
    const int n0 = (xi & 7) * 128;
    const int t = xi >> 3;               // 0..95
    const int c0 = (t % 12) * 32;
    const int b = t / 12;
    {
        int c = tid >> 3, nq = (tid & 7) * 16;
        const float* sp = x1 + ((size_t)b*C + c0 + c)*N + n0 + nq;
        #pragma unroll
        for (int i = 0; i < 4; ++i)
            *(float4*)&tile[c][nq + 4*i] = *(const float4*)(sp + 4*i);
    }
    __syncthreads();
    {
        int n = tid >> 1, cb = (tid & 1) * 16;
        unsigned short* dp = x1T + ((size_t)b*N + n0 + n)*C + c0 + cb;
        #pragma unroll
        for (int half = 0; half < 2; ++half) {
            bf16x8 v;
            #pragma unroll
            for (int j = 0; j < 8; ++j)
                v[j] = (short)bf16_bits(tile[cb + half*8 + j][n]);
            *(bf16x8*)(dp + half*8) = v;
        }
    }
}

// ---------------------------------------------------------------------------
// MFMA projection: acc[n][o] = sum_c XT[n][c] * Wb[o][c]; bf16 weights.
// MODE 2: out fp32 spatial + bias + residual
// MODE 3: out bf16 token-major + bias  AND bf16 spatial + bias
// ---------------------------------------------------------------------------
template<int MODE>
__global__ __launch_bounds__(256) void proj_mfma(const unsigned short* __restrict__ XT,
                                                 const unsigned short* __restrict__ Wb,
                                                 const float* __restrict__ bias,
                                                 const float* __restrict__ res,
                                                 void* __restrict__ out,
                                                 void* __restrict__ out2)
{
    __shared__ __align__(16) char smem[64*72*2*2];   // 18,432 B
    unsigned short* sA = (unsigned short*)smem;      // [64n][72c]
    unsigned short* sB = sA + 64*72;                 // [64o][72c]
    float* ep = (float*)smem;                        // epilogue [64n][65o]

    const int tid = threadIdx.x;
    const int lane = tid & 63, w = tid >> 6;
    const int l15 = lane & 15, lq = lane >> 4;
    const int n0 = blockIdx.x * 64, o0 = blockIdx.y * 64, b = blockIdx.z;
    const int qn = (w & 1) * 32, qo = (w >> 1) * 32;

    const unsigned short* xg = XT + ((size_t)b*N + n0)*C;
    const unsigned short* wg = Wb + (size_t)o0*C;

    const f32x4 zero = {0.f, 0.f, 0.f, 0.f};
    f32x4 a00 = zero, a01 = zero, a10 = zero, a11 = zero;

    const int r = tid >> 2, c8 = (tid & 3) * 8;
    for (int c0 = 0; c0 < C; c0 += 64) {
        __syncthreads();
        *(bf16x8*)(sA + r*72 + c8)      = *(const bf16x8*)(xg + (size_t)r*C + c0 + c8);
        *(bf16x8*)(sA + r*72 + c8 + 32) = *(const bf16x8*)(xg + (size_t)r*C + c0 + c8 + 32);
        *(bf16x8*)(sB + r*72 + c8)      = *(const bf16x8*)(wg + (size_t)r*C + c0 + c8);
        *(bf16x8*)(sB + r*72 + c8 + 32) = *(const bf16x8*)(wg + (size_t)r*C + c0 + c8 + 32);
        __syncthreads();
        #pragma unroll
        for (int ks = 0; ks < 2; ++ks) {
            bf16x8 fa0 = *(const bf16x8*)(sA + (qn + l15)*72      + ks*32 + lq*8);
            bf16x8 fa1 = *(const bf16x8*)(sA + (qn + 16 + l15)*72 + ks*32 + lq*8);
            bf16x8 fb0 = *(const bf16x8*)(sB + (qo + l15)*72      + ks*32 + lq*8);
            bf16x8 fb1 = *(const bf16x8*)(sB + (qo + 16 + l15)*72 + ks*32 + lq*8);
            a00 = __builtin_amdgcn_mfma_f32_16x16x32_bf16(fa0, fb0, a00, 0, 0, 0);
            a01 = __builtin_amdgcn_mfma_f32_16x16x32_bf16(fa0, fb1, a01, 0, 0, 0);
            a10 = __builtin_amdgcn_mfma_f32_16x16x32_bf16(fa1, fb0, a10, 0, 0, 0);
            a11 = __builtin_amdgcn_mfma_f32_16x16x32_bf16(fa1, fb1, a11, 0, 0, 0);
        }
    }
    __syncthreads();
    #pragma unroll
    for (int rr = 0; rr < 4; ++rr) {
        int nr0 = qn + 4*lq + rr, nr1 = qn + 16 + 4*lq + rr;
        ep[nr0*65 + qo + l15]      = a00[rr];
        ep[nr0*65 + qo + 16 + l15] = a01[rr];
        ep[nr1*65 + qo + l15]      = a10[rr];
        ep[nr1*65 + qo + 16 + l15] = a11[rr];
    }
    __syncthreads();

    if constexpr (MODE == 3) {
        {   // token-major bf16
            int n = tid >> 2, ch = tid & 3;
            unsigned short* op = (unsigned short*)out + ((size_t)b*N + n0 + n)*C + o0;
            #pragma unroll
            for (int half = 0; half < 2; ++half) {
                int ob = ch*8 + half*32;
                bf16x8 v;
                #pragma unroll
                for (int j = 0; j < 8; ++j)
                    v[j] = (short)bf16_bits(ep[n*65 + ob + j] + bias[o0 + ob + j]);
                *(bf16x8*)(op + ob) = v;
            }
        }
        {   // bf16 spatial (for dwconv)
            int o = tid >> 2, nc = (tid & 3) * 16;
            float bz = bias[o0 + o];
            unsigned short* dp = (unsigned short*)out2 + ((size_t)b*C + o0 + o)*N + n0 + nc;
            #pragma unroll
            for (int half = 0; half < 2; ++half) {
                bf16x8 v;
                #pragma unroll
                for (int j = 0; j < 8; ++j)
                    v[j] = (short)bf16_bits(ep[(nc + half*8 + j)*65 + o] + bz);
                *(bf16x8*)(dp + half*8) = v;
            }
        }
    } else {
        int o = tid >> 2, nc = (tid & 3) * 16;
        float bz = bias[o0 + o];
        size_t base = ((size_t)b*C + o0 + o)*N + n0 + nc;
        #pragma unroll
        for (int i = 0; i < 4; ++i) {
            float4 rv = *(const float4*)(res + base + 4*i);
            f32x4 v;
            v[0] = ep[(nc + 4*i + 0)*65 + o] + bz + rv.x;
            v[1] = ep[(nc + 4*i + 1)*65 + o] + bz + rv.y;
            v[2] = ep[(nc + 4*i + 2)*65 + o] + bz + rv.z;
            v[3] = ep[(nc + 4*i + 3)*65 + o] + bz + rv.w;
            __builtin_nontemporal_store(v, (f32x4*)((float*)out + base + 4*i));
        }
    }
}

// ---------------------------------------------------------------------------
// Fused K+V projection (bf16 weights). One sampT staging, two outputs.
// K scaled by KSCALE (matches attention's exp flavor).
// ---------------------------------------------------------------------------
__global__ __launch_bounds__(256) void proj_kv(const unsigned short* __restrict__ XT,
                                               const unsigned short* __restrict__ Wk,
                                               const float* __restrict__ bk,
                                               const unsigned short* __restrict__ Wv,
                                               const float* __restrict__ bv,
                                               unsigned short* __restrict__ K16,
                                               unsigned short* __restrict__ V16)
{
    __shared__ __align__(16) char smem[64*72*2*3];   // 27,648 B
    unsigned short* sA  = (unsigned short*)smem;
    unsigned short* sBk = sA + 64*72;
    unsigned short* sBv = sA + 2*64*72;
    float* ep = (float*)smem;                        // [64n][65o]

    const int tid = threadIdx.x;
    const int lane = tid & 63, w = tid >> 6;
    const int l15 = lane & 15, lq = lane >> 4;
    const int n0 = blockIdx.x * 64, o0 = blockIdx.y * 64, b = blockIdx.z;
    const int qn = (w & 1) * 32, qo = (w >> 1) * 32;

    const unsigned short* xg = XT + ((size_t)b*N + n0)*C;
    const unsigned short* wkg = Wk + (size_t)o0*C;
    const unsigned short* wvg = Wv + (size_t)o0*C;

    const f32x4 zero = {0.f, 0.f, 0.f, 0.f};
    f32x4 k00 = zero, k01 = zero, k10 = zero, k11 = zero;
    f32x4 v00 = zero, v01 = zero, v10 = zero, v11 = zero;

    const int r = tid >> 2, c8 = (tid & 3) * 8;
    for (int c0 = 0; c0 < C; c0 += 64) {
        __syncthreads();
        *(bf16x8*)(sA  + r*72 + c8)      = *(const bf16x8*)(xg  + (size_t)r*C + c0 + c8);
        *(bf16x8*)(sA  + r*72 + c8 + 32) = *(const bf16x8*)(xg  + (size_t)r*C + c0 + c8 + 32);
        *(bf16x8*)(sBk + r*72 + c8)      = *(const bf16x8*)(wkg + (size_t)r*C + c0 + c8);
        *(bf16x8*)(sBk + r*72 + c8 + 32) = *(const bf16x8*)(wkg + (size_t)r*C + c0 + c8 + 32);
        *(bf16x8*)(sBv + r*72 + c8)      = *(const bf16x8*)(wvg + (size_t)r*C + c0 + c8);
        *(bf16x8*)(sBv + r*72 + c8 + 32) = *(const bf16x8*)(wvg + (size_t)r*C + c0 + c8 + 32);
        __syncthreads();
        #pragma unroll
        for (int ks = 0; ks < 2; ++ks) {
            bf16x8 fa0 = *(const bf16x8*)(sA + (qn + l15)*72      + ks*32 + lq*8);
            bf16x8 fa1 = *(const bf16x8*)(sA + (qn + 16 + l15)*72 + ks*32 + lq*8);
            bf16x8 fk0 = *(const bf16x8*)(sBk + (qo + l15)*72      + ks*32 + lq*8);
            bf16x8 fk1 = *(const bf16x8*)(sBk + (qo + 16 + l15)*72 + ks*32 + lq*8);
            bf16x8 fv0 = *(const bf16x8*)(sBv + (qo + l15)*72      + ks*32 + lq*8);
            bf16x8 fv1 = *(const bf16x8*)(sBv + (qo + 16 + l15)*72 + ks*32 + lq*8);
            k00 = __builtin_amdgcn_mfma_f32_16x16x32_bf16(fa0, fk0, k00, 0, 0, 0);
            k01 = __builtin_amdgcn_mfma_f32_16x16x32_bf16(fa0, fk1, k01, 0, 0, 0);
            k10 = __builtin_amdgcn_mfma_f32_16x16x32_bf16(fa1, fk0, k10, 0, 0, 0);
            k11 = __builtin_amdgcn_mfma_f32_16x16x32_bf16(fa1, fk1, k11, 0, 0, 0);
            v00 = __builtin_amdgcn_mfma_f32_16x16x32_bf16(fa0, fv0, v00, 0, 0, 0);
            v01 = __builtin_amdgcn_mfma_f32_16x16x32_bf16(fa0, fv1, v01, 0, 0, 0);
            v10 = __builtin_amdgcn_mfma_f32_16x16x32_bf16(fa1, fv0, v10, 0, 0, 0);
            v11 = __builtin_amdgcn_mfma_f32_16x16x32_bf16(fa1, fv1, v11, 0, 0, 0);
        }
    }
    // ---- K epilogue (token-major bf16, *KSCALE) ----
    __syncthreads();
    #pragma unroll
    for (int rr = 0; rr < 4; ++rr) {
        int nr0 = qn + 4*lq + rr, nr1 = qn + 16 + 4*lq + rr;
        ep[nr0*65 + qo + l15]      = k00[rr];
        ep[nr0*65 + qo + 16 + l15] = k01[rr];
        ep[nr1*65 + qo + l15]      = k10[rr];
        ep[nr1*65 + qo + 16 + l15] = k11[rr];
    }
    __syncthreads();
    {
        int n = tid >> 2, ch = tid & 3;
        unsigned short* op = K16 + ((size_t)b*N + n0 + n)*C + o0;
        #pragma unroll
        for (int half = 0; half < 2; ++half) {
            int ob = ch*8 + half*32;
            bf16x8 v;
            #pragma unroll
            for (int j = 0; j < 8; ++j)
                v[j] = (short)bf16_bits((ep[n*65 + ob + j] + bk[o0 + ob + j]) * KSCALE);
            *(bf16x8*)(op + ob) = v;
        }
    }
    // ---- V epilogue (spatial bf16) ----
    __syncthreads();
    #pragma unroll
    for (int rr = 0; rr < 4; ++rr) {
        int nr0 = qn + 4*lq + rr, nr1 = qn + 16 + 4*lq + rr;
        ep[nr0*65 + qo + l15]      = v00[rr];
        ep[nr0*65 + qo + 16 + l15] = v01[rr];
        ep[nr1*65 + qo + l15]      = v10[rr];
        ep[nr1*65 + qo + 16 + l15] = v11[rr];
    }
    __syncthreads();
    {
        int o = tid >> 2, nc = (tid & 3) * 16;
        float bz = bv[o0 + o];
        unsigned short* op = V16 + ((size_t)b*C + o0 + o)*N + n0 + nc;
        #pragma unroll
        for (int half = 0; half < 2; ++half) {
            bf16x8 v;
            #pragma unroll
            for (int j = 0; j < 8; ++j)
                v[j] = (short)bf16_bits(ep[(nc + half*8 + j)*65 + o] + bz);
            *(bf16x8*)(op + half*8) = v;
        }
    }
}

// ---------------------------------------------------------------------------
// Depthwise 5x5 conv (SAME, zero-pad) + bias + tanh GELU, halo-tiled in LDS.
// bf16 in, bf16 out. grid (4, 128, 24)
// ---------------------------------------------------------------------------
__global__ __launch_bounds__(256) void dwconv_gelu(const unsigned short* __restrict__ q,
                                                   const float* __restrict__ wdw,
                                                   const float* __restrict__ bdw,
                                                   unsigned short* __restrict__ t)
{
    __shared__ float tile[12][32];
    __shared__ float wsm[25];
    const int bx = blockIdx.x;           // 0..3 (8-row stripes)
    const int c = blockIdx.y, bg = blockIdx.z;
    const int tid = threadIdx.x;
    const unsigned short* qc = q + ((size_t)bg*Cg + c)*N;
    if (tid < 384) {
        int row = tid >> 5, col = tid & 31;
        int gy = bx*8 - 2 + row;
        tile[row][col] = (gy >= 0 && gy < H) ? bf2f(qc[gy*W + col]) : 0.0f;
    }
    if (tid < 25) wsm[tid] = wdw[c*25 + tid];
    __syncthreads();
    const int yl = tid >> 5, x = tid & 31;
    float acc = bdw[c];
    #pragma unroll
    for (int ky = 0; ky < 5; ++ky) {
        #pragma unroll
        for (int kx = 0; kx < 5; ++kx) {
            int xx = x + kx - 2;
            if (xx < 0 || xx >= W) continue;
            acc += wsm[ky*5 + kx] * tile[yl + ky][xx];
        }
    }
    float u = acc;
    float g = 0.5f*u*(1.0f + fast_tanh(0.7978845608028654f*(u + 0.044715f*u*u*u)));
    t[((size_t)bg*Cg + c)*N + bx*256 + tid] = bf16_bits(g);
}

// ---------------------------------------------------------------------------
// Merged: pointwise conv(2) + tanh + grid + bilinear gather -> sampT bf16.
// Reads bf16 tbuf. grid (16, 24)
// ---------------------------------------------------------------------------
__global__ __launch_bounds__(256) void offbilin(const unsigned short* __restrict__ t,
                                                const float* __restrict__ wpw,
                                                const float* __restrict__ bpw,
                                                const float* __restrict__ x2,
                                                unsigned short* __restrict__ sampT)
{
    __shared__ float r0[4][64], r1[4][64];
    __shared__ float4 cbuf[64];
    __shared__ unsigned short st[64][130];
    const int tid = threadIdx.x;
    const int n0 = blockIdx.x * 64, bg = blockIdx.y;
    const int nl = tid & 63, cq = tid >> 6;
    {
        const unsigned short* tb = t + ((size_t)bg*Cg + cq*32)*N + n0 + nl;
        float a0 = 0.f, a1 = 0.f;
        #pragma unroll 8
        for (int i = 0; i < 32; ++i) {
            float tv = bf2f(tb[(size_t)i*N]);
            a0 += wpw[cq*32 + i] * tv;
            a1 += wpw[Cg + cq*32 + i] * tv;
        }
        r0[cq][nl] = a0; r1[cq][nl] = a1;
    }
    __syncthreads();
    if (tid < 64) {
        int n = n0 + nl;
        const int x = n & 31, y = n >> 5;
        float a0 = bpw[0] + r0[0][nl] + r0[1][nl] + r0[2][nl] + r0[3][nl];
        float a1 = bpw[1] + r1[0][nl] + r1[1][nl] + r1[2][nl] + r1[3][nl];
        float dx = fast_tanh(a0) * (2.0f / W);
        float dy = fast_tanh(a1) * (2.0f / H);
        float rx = (x + 0.5f) / W * 2.0f - 1.0f;
        float ry = (y + 0.5f) / H * 2.0f - 1.0f;
        float px = fminf(fmaxf(rx + dx, -1.0f), 1.0f);
        float py = fminf(fmaxf(ry + dy, -1.0f), 1.0f);
        float gx = (px + 1.0f) * 0.5f * (W - 1);
        float gy = (py + 1.0f) * 0.5f * (H - 1);
        float x0 = floorf(gx), y0 = floorf(gy);
        float wx1 = gx - x0, wy1 = gy - y0;
        x0 = fminf(fmaxf(x0, 0.0f), (float)(W - 1));
        y0 = fminf(fmaxf(y0, 0.0f), (float)(H - 1));
        cbuf[nl] = make_float4(x0, y0, wx1, wy1);
    }
    __syncthreads();
    {
        float4 c4 = cbuf[nl];
        int x0 = (int)c4.x, y0 = (int)c4.y;
        float wx1 = c4.z, wy1 = c4.w;
        int x1 = min(x0 + 1, W - 1), y1 = min(y0 + 1, H - 1);
        float wx0 = 1.0f - wx1, wy0 = 1.0f - wy1;
        const float* base = x2 + (size_t)bg*Cg*N;
        #pragma unroll 4
        for (int i = 0; i < 32; ++i) {
            int c = cq*32 + i;
            const float* img = base + (size_t)c*N;
            float v00 = img[y0*W + x0], v01 = img[y0*W + x1];
            float v10 = img[y1*W + x0], v11 = img[y1*W + x1];
            float v = wy0*(wx0*v00 + wx1*v01) + wy1*(wx0*v10 + wx1*v11);
            st[nl][c] = bf16_bits(v);
        }
    }
    __syncthreads();
    {
        int b = bg / 3, g = bg % 3;
        int nn = tid >> 2;
        unsigned short* dp = sampT + ((size_t)b*N + n0 + nn)*C + g*Cg;
        #pragma unroll
        for (int i = 0; i < 4; ++i) {
            int c8 = ((tid & 3) + 4*i) * 8;
            *(bf16x8*)(dp + c8) = *(const bf16x8*)&st[nn][c8];
        }
    }
}

// ---------------------------------------------------------------------------
// Fused attention (R12 structure): 2-pass, LDS-staged K/V, transposed
// row-contiguous NT attn stores. LDS 46.6KB -> 3 blocks/CU. grid (1536).
// exp flavor matches KSCALE (fexp = v_exp_f32 or __expf).
// ---------------------------------------------------------------------------
__global__ __launch_bounds__(256) void attn_fused(const unsigned short* __restrict__ Q16,
                                                  const unsigned short* __restrict__ K16,
                                                  const unsigned short* __restrict__ V16,
                                                  float* __restrict__ attn,
                                                  unsigned short* __restrict__ OT)
{
    __shared__ __align__(16) unsigned short ks[256*40];    // 20,480 B
    __shared__ __align__(16) unsigned short vs[32*264];    // 16,896 B
    __shared__ __align__(16) unsigned short ps[4][16*72];  //  9,216 B

    const int tid = threadIdx.x;
    const int lane = tid & 63, w = tid >> 6;
    const int l15 = lane & 15, lq = lane >> 4;
    const int id = blockIdx.x;
    const int xcd = id & 7, j = id >> 3;
    const int bh = xcd*12 + (j >> 4);
    const int nb = j & 15;
    const int b = bh / HEADS, h = bh - b*HEADS;

    const unsigned short* qg = Q16 + ((size_t)b*N + nb*64)*C + h*32;
    const unsigned short* kg = K16 + (size_t)b*N*C + h*32;
    const unsigned short* vg = V16 + ((size_t)b*C + h*32)*N;

    const bf16x8 qfrag = *(const bf16x8*)(qg + (size_t)(w*16 + l15)*C + lq*8);

    const f32x4 zero = {0.f, 0.f, 0.f, 0.f};
    float sm = 0.f;
    f32x4 s[16];

    // ---------------- PASS 1: row sums only ----------------
    for (int ch = 0; ch < 4; ++ch) {
        __syncthreads();
        #pragma unroll
        for (int i = 0; i < 4; ++i) {
            int m = i*64 + (tid >> 2), c8 = (tid & 3) * 8;
            *(bf16x8*)(ks + m*40 + c8) = *(const bf16x8*)(kg + ((size_t)ch*256 + m)*C + c8);
        }
        __syncthreads();
        #pragma unroll
        for (int t = 0; t < 16; ++t) {
            bf16x8 kfrag = *(const bf16x8*)(ks + (16*t + l15)*40 + lq*8);
            s[t] = __builtin_amdgcn_mfma_f32_16x16x32_bf16(kfrag, qfrag, zero, 0, 0, 0);
        }
        float es = 0.f;
        #pragma unroll
        for (int t = 0; t < 16; ++t) {
            es += fexp(s[t][0]); es += fexp(s[t][1]);
            es += fexp(s[t][2]); es += fexp(s[t][3]);
        }
        sm += es;
    }
    sm += __shfl_xor(sm, 16);
    sm += __shfl_xor(sm, 32);
    const float inv = 1.0f / sm;

    // ---------------- PASS 2: recompute + P write + PV ----------------
    f32x4 outf[2] = {zero, zero};
    unsigned short* pw = ps[w];
    float* abase = attn + ((size_t)bh*N + (size_t)nb*64 + w*16)*N;
    const int trow = lane >> 4;
    const int tcol = (lane & 15) * 4;

    for (int ch = 0; ch < 4; ++ch) {
        __syncthreads();
        #pragma unroll
        for (int i = 0; i < 4; ++i) {
            int m = i*64 + (tid >> 2), c8 = (tid & 3) * 8;
            *(bf16x8*)(ks + m*40 + c8) = *(const bf16x8*)(kg + ((size_t)ch*256 + m)*C + c8);
        }
        #pragma unroll
        for (int i = 0; i < 4; ++i) {
            int u = tid + i*256;
            int cl = u >> 5, gg = u & 31;
            *(bf16x8*)(vs + cl*264 + gg*8) = *(const bf16x8*)(vg + (size_t)cl*N + ch*256 + gg*8);
        }
        __syncthreads();
        #pragma unroll
        for (int t = 0; t < 16; ++t) {
            bf16x8 kfrag = *(const bf16x8*)(ks + (16*t + l15)*40 + lq*8);
            s[t] = __builtin_amdgcn_mfma_f32_16x16x32_bf16(kfrag, qfrag, zero, 0, 0, 0);
        }
        #pragma unroll
        for (int qr = 0; qr < 4; ++qr) {
            #pragma unroll
            for (int tt = 0; tt < 4; ++tt) {
                int t = qr*4 + tt;
                float e0 = fexp(s[t][0]), e1 = fexp(s[t][1]);
                float e2 = fexp(s[t][2]), e3 = fexp(s[t][3]);
                uint2 pb;
                pb.x = (unsigned)bf16_bits(e0) | ((unsigned)bf16_bits(e1) << 16);
                pb.y = (unsigned)bf16_bits(e2) | ((unsigned)bf16_bits(e3) << 16);
                *(uint2*)(pw + l15*72 + 16*tt + 4*lq) = pb;
            }
            __asm volatile("" ::: "memory");
            #pragma unroll
            for (int kk = 0; kk < 2; ++kk) {
                bf16x8 pa = *(const bf16x8*)(pw + l15*72 + kk*32 + lq*8);
                #pragma unroll
                for (int ct = 0; ct < 2; ++ct) {
                    bf16x8 vb = *(const bf16x8*)(vs + (16*ct + l15)*264 + qr*64 + kk*32 + lq*8);
                    outf[ct] = __builtin_amdgcn_mfma_f32_16x16x32_bf16(pa, vb, outf[ct], 0, 0, 0);
                }
            }
            #pragma unroll
            for (int it = 0; it < 4; ++it) {
                int row = it*4 + trow;
                uint2 u = *(const uint2*)(pw + row*72 + tcol);
                float invr = __shfl(inv, row);
                f32x4 p;
                p[0] = __builtin_bit_cast(float, u.x << 16) * invr;
                p[1] = __builtin_bit_cast(float, u.x & 0xffff0000u) * invr;
                p[2] = __builtin_bit_cast(float, u.y << 16) * invr;
                p[3] = __builtin_bit_cast(float, u.y & 0xffff0000u) * invr;
                __builtin_nontemporal_store(p,
                    (f32x4*)(abase + (size_t)row*N + ch*256 + qr*64 + tcol));
            }
            __asm volatile("" ::: "memory");
        }
    }

    // epilogue: fold inv (per output row n = 4lq+r) into PV result
    float* sc = (float*)pw;   // [16n][33c]
    #pragma unroll
    for (int r = 0; r < 4; ++r) {
        float invr = __shfl(inv, 4*lq + r);
        sc[(4*lq + r)*33 + l15]      = outf[0][r] * invr;
        sc[(4*lq + r)*33 + 16 + l15] = outf[1][r] * invr;
    }
    __asm volatile("" ::: "memory");
    {
        int n = lane >> 2, c8 = (lane & 3) * 8;
        bf16x8 v;
        #pragma unroll
        for (int j2 = 0; j2 < 8; ++j2)
            v[j2] = (short)bf16_bits(sc[n*33 + c8 + j2]);
        *(bf16x8*)(OT + ((size_t)b*N + nb*64 + w*16 + n)*C + h*32 + c8) = v;
    }
}

// ---------------------------------------------------------------------------
extern "C" void kernel_launch(void* const* d_in, const int* in_sizes, int n_in,
                              void* d_out, int out_size, void* d_ws, size_t ws_size,
                              hipStream_t stream)
{
    const float* x1  = (const float*)d_in[0];
    const float* x2  = (const float*)d_in[1];
    const float* wq  = (const float*)d_in[2];
    const float* bq  = (const float*)d_in[3];
    const float* wdw = (const float*)d_in[4];
    const float* bdw = (const float*)d_in[5];
    const float* wpw = (const float*)d_in[6];
    const float* bpw = (const float*)d_in[7];
    const float* wk  = (const float*)d_in[8];
    const float* bk  = (const float*)d_in[9];
    const float* wv  = (const float*)d_in[10];
    const float* bv  = (const float*)d_in[11];
    const float* wo  = (const float*)d_in[12];
    const float* bo  = (const float*)d_in[13];

    const size_t P = (size_t)B * C * N;          // 3,145,728 floats
    float* ws = (float*)d_ws;
    unsigned short* Q16   = (unsigned short*)ws;             // P ushorts
    unsigned short* qspat = (unsigned short*)(ws + P/2);     // P ushorts (bf16 spatial)
    unsigned short* sampT = (unsigned short*)(ws + P);       // P ushorts
    unsigned short* K16   = (unsigned short*)(ws + 3*P/2);   // P ushorts
    unsigned short* V16   = (unsigned short*)(ws + 2*P);     // P ushorts
    unsigned short* x1T   = (unsigned short*)(ws + 5*P/2);   // P ushorts, reused as OT
    unsigned short* OT    = x1T;
    unsigned short* tbuf  = (unsigned short*)(ws + 3*P);     // P ushorts (bf16)
    unsigned short* w16   = (unsigned short*)(ws + 7*P/2);   // 4*147456 halves
    unsigned short* w16q = w16;
    unsigned short* w16k = w16 + 147456;
    unsigned short* w16v = w16 + 2*147456;
    unsigned short* w16o = w16 + 3*147456;

    float* ybuf = (float*)d_out;                 // (B,C,H,W)
    float* attn = (float*)d_out + P;             // (B,HEADS,N,N)

    prep<<<dim3(1056), 256, 0, stream>>>(wq, wk, wv, wo, x1, w16, x1T);
    proj_mfma<3><<<dim3(16, 6, 8), 256, 0, stream>>>(x1T, w16q, bq, nullptr, Q16, qspat);
    dwconv_gelu<<<dim3(4, Cg, BG), 256, 0, stream>>>(qspat, wdw, bdw, tbuf);
    offbilin<<<dim3(16, BG), 256, 0, stream>>>(tbuf, wpw, bpw, x2, sampT);
    proj_kv<<<dim3(16, 6, 8), 256, 0, stream>>>(sampT, w16k, bk, w16v, bv, K16, V16);
    attn_fused<<<dim3(1536), 256, 0, stream>>>(Q16, K16, V16, attn, OT);
    proj_mfma<2><<<dim3(16, 6, 8), 256, 0, stream>>>(OT, w16o, bo, x1, ybuf, nullptr);
}

// Round 16
// 155.932 us; speedup vs baseline: 1.4531x; 1.0819x over previous
//
#include <hip/hip_runtime.h>
#include <hip/hip_bf16.h>

static constexpr int B = 8;
static constexpr int C = 384;
static constexpr int H = 32;
static constexpr int W = 32;
static constexpr int N = 1024;      // H*W
static constexpr int Cg = 128;      // C/G
static constexpr int HEADS = 12;
static constexpr int BG = 24;      // B*G
static constexpr float SCALE = 0.17677669529663687f; // hc^-0.5

typedef short bf16x8 __attribute__((ext_vector_type(8)));
typedef float f32x4 __attribute__((ext_vector_type(4)));

__device__ __forceinline__ unsigned short bf16_bits(float x) {
    __hip_bfloat16 h = __float2bfloat16(x);
    return __builtin_bit_cast(unsigned short, h);
}
__device__ __forceinline__ float bf2f(unsigned short u) {
    return __builtin_bit_cast(float, ((unsigned)u) << 16);
}
__device__ __forceinline__ float fast_tanh(float x) {
    float e = __expf(2.0f * x);
    return 1.0f - 2.0f / (e + 1.0f);
}

// ---------------------------------------------------------------------------
// prep: blocks 0..287 convert 4 weight matrices to bf16 (one-time);
// blocks 288..1055 transpose x1 fp32 -> bf16 token-major [b][1024][384].
// ---------------------------------------------------------------------------
__global__ __launch_bounds__(256) void prep(const float* __restrict__ wq,
                                            const float* __restrict__ wk,
                                            const float* __restrict__ wv,
                                            const float* __restrict__ wo,
                                            const float* __restrict__ x1,
                                            unsigned short* __restrict__ w16,
                                            unsigned short* __restrict__ x1T)
{
    __shared__ float tile[32][132];
    const int bx = blockIdx.x;
    const int tid = threadIdx.x;
    if (bx < 288) {
        int which = bx / 72, blk = bx - which*72;
        const float* src = (which == 0) ? wq : (which == 1) ? wk : (which == 2) ? wv : wo;
        int idx = (blk*256 + tid) * 8;
        const float4* p = (const float4*)(src + idx);
        float4 f0 = p[0], f1 = p[1];
        uint4 u;
        u.x = (unsigned)bf16_bits(f0.x) | ((unsigned)bf16_bits(f0.y) << 16);
        u.y = (unsigned)bf16_bits(f0.z) | ((unsigned)bf16_bits(f0.w) << 16);
        u.z = (unsigned)bf16_bits(f1.x) | ((unsigned)bf16_bits(f1.y) << 16);
        u.w = (unsigned)bf16_bits(f1.z) | ((unsigned)bf16_bits(f1.w) << 16);
        *(uint4*)(w16 + (size_t)which * 147456 + idx) = u;
        return;
    }
    const int xi = bx - 288;
    const int n0 = (xi & 7) * 128;
    const int t = xi >> 3;               // 0..95
    const int c0 = (t % 12) * 32;
    const int b = t / 12;
    {
        int c = tid >> 3, nq = (tid & 7) * 16;
        const float* sp = x1 + ((size_t)b*C + c0 + c)*N + n0 + nq;
        #pragma unroll
        for (int i = 0; i < 4; ++i)
            *(float4*)&tile[c][nq + 4*i] = *(const float4*)(sp + 4*i);
    }
    __syncthreads();
    {
        int n = tid >> 1, cb = (tid & 1) * 16;
        unsigned short* dp = x1T + ((size_t)b*N + n0 + n)*C + c0 + cb;
        #pragma unroll
        for (int half = 0; half < 2; ++half) {
            bf16x8 v;
            #pragma unroll
            for (int j = 0; j < 8; ++j)
                v[j] = (short)bf16_bits(tile[cb + half*8 + j][n]);
            *(bf16x8*)(dp + half*8) = v;
        }
    }
}

// ---------------------------------------------------------------------------
// MFMA projection: acc[n][o] = sum_c XT[n][c] * Wb[o][c]; bf16 weights.
// MODE 2: out fp32 spatial + bias + residual
// MODE 3: out bf16 token-major + bias  AND bf16 spatial + bias
// ---------------------------------------------------------------------------
template<int MODE>
__global__ __launch_bounds__(256) void proj_mfma(const unsigned short* __restrict__ XT,
                                                 const unsigned short* __restrict__ Wb,
                                                 const float* __restrict__ bias,
                                                 const float* __restrict__ res,
                                                 void* __restrict__ out,
                                                 void* __restrict__ out2)
{
    __shared__ __align__(16) char smem[64*72*2*2];   // 18,432 B
    unsigned short* sA = (unsigned short*)smem;      // [64n][72c]
    unsigned short* sB = sA + 64*72;                 // [64o][72c]
    float* ep = (float*)smem;                        // epilogue [64n][65o]

    const int tid = threadIdx.x;
    const int lane = tid & 63, w = tid >> 6;
    const int l15 = lane & 15, lq = lane >> 4;
    const int n0 = blockIdx.x * 64, o0 = blockIdx.y * 64, b = blockIdx.z;
    const int qn = (w & 1) * 32, qo = (w >> 1) * 32;

    const unsigned short* xg = XT + ((size_t)b*N + n0)*C;
    const unsigned short* wg = Wb + (size_t)o0*C;

    const f32x4 zero = {0.f, 0.f, 0.f, 0.f};
    f32x4 a00 = zero, a01 = zero, a10 = zero, a11 = zero;

    const int r = tid >> 2, c8 = (tid & 3) * 8;
    for (int c0 = 0; c0 < C; c0 += 64) {
        __syncthreads();
        *(bf16x8*)(sA + r*72 + c8)      = *(const bf16x8*)(xg + (size_t)r*C + c0 + c8);
        *(bf16x8*)(sA + r*72 + c8 + 32) = *(const bf16x8*)(xg + (size_t)r*C + c0 + c8 + 32);
        *(bf16x8*)(sB + r*72 + c8)      = *(const bf16x8*)(wg + (size_t)r*C + c0 + c8);
        *(bf16x8*)(sB + r*72 + c8 + 32) = *(const bf16x8*)(wg + (size_t)r*C + c0 + c8 + 32);
        __syncthreads();
        #pragma unroll
        for (int ks = 0; ks < 2; ++ks) {
            bf16x8 fa0 = *(const bf16x8*)(sA + (qn + l15)*72      + ks*32 + lq*8);
            bf16x8 fa1 = *(const bf16x8*)(sA + (qn + 16 + l15)*72 + ks*32 + lq*8);
            bf16x8 fb0 = *(const bf16x8*)(sB + (qo + l15)*72      + ks*32 + lq*8);
            bf16x8 fb1 = *(const bf16x8*)(sB + (qo + 16 + l15)*72 + ks*32 + lq*8);
            a00 = __builtin_amdgcn_mfma_f32_16x16x32_bf16(fa0, fb0, a00, 0, 0, 0);
            a01 = __builtin_amdgcn_mfma_f32_16x16x32_bf16(fa0, fb1, a01, 0, 0, 0);
            a10 = __builtin_amdgcn_mfma_f32_16x16x32_bf16(fa1, fb0, a10, 0, 0, 0);
            a11 = __builtin_amdgcn_mfma_f32_16x16x32_bf16(fa1, fb1, a11, 0, 0, 0);
        }
    }
    __syncthreads();
    #pragma unroll
    for (int rr = 0; rr < 4; ++rr) {
        int nr0 = qn + 4*lq + rr, nr1 = qn + 16 + 4*lq + rr;
        ep[nr0*65 + qo + l15]      = a00[rr];
        ep[nr0*65 + qo + 16 + l15] = a01[rr];
        ep[nr1*65 + qo + l15]      = a10[rr];
        ep[nr1*65 + qo + 16 + l15] = a11[rr];
    }
    __syncthreads();

    if constexpr (MODE == 3) {
        {   // token-major bf16
            int n = tid >> 2, ch = tid & 3;
            unsigned short* op = (unsigned short*)out + ((size_t)b*N + n0 + n)*C + o0;
            #pragma unroll
            for (int half = 0; half < 2; ++half) {
                int ob = ch*8 + half*32;
                bf16x8 v;
                #pragma unroll
                for (int j = 0; j < 8; ++j)
                    v[j] = (short)bf16_bits(ep[n*65 + ob + j] + bias[o0 + ob + j]);
                *(bf16x8*)(op + ob) = v;
            }
        }
        {   // bf16 spatial (for dwconv)
            int o = tid >> 2, nc = (tid & 3) * 16;
            float bz = bias[o0 + o];
            unsigned short* dp = (unsigned short*)out2 + ((size_t)b*C + o0 + o)*N + n0 + nc;
            #pragma unroll
            for (int half = 0; half < 2; ++half) {
                bf16x8 v;
                #pragma unroll
                for (int j = 0; j < 8; ++j)
                    v[j] = (short)bf16_bits(ep[(nc + half*8 + j)*65 + o] + bz);
                *(bf16x8*)(dp + half*8) = v;
            }
        }
    } else {
        int o = tid >> 2, nc = (tid & 3) * 16;
        float bz = bias[o0 + o];
        size_t base = ((size_t)b*C + o0 + o)*N + n0 + nc;
        #pragma unroll
        for (int i = 0; i < 4; ++i) {
            float4 rv = *(const float4*)(res + base + 4*i);
            f32x4 v;
            v[0] = ep[(nc + 4*i + 0)*65 + o] + bz + rv.x;
            v[1] = ep[(nc + 4*i + 1)*65 + o] + bz + rv.y;
            v[2] = ep[(nc + 4*i + 2)*65 + o] + bz + rv.z;
            v[3] = ep[(nc + 4*i + 3)*65 + o] + bz + rv.w;
            __builtin_nontemporal_store(v, (f32x4*)((float*)out + base + 4*i));
        }
    }
}

// ---------------------------------------------------------------------------
// Fused K+V projection (bf16 weights). One sampT staging, two outputs.
// K scaled by SCALE (attention uses __expf).
// ---------------------------------------------------------------------------
__global__ __launch_bounds__(256) void proj_kv(const unsigned short* __restrict__ XT,
                                               const unsigned short* __restrict__ Wk,
                                               const float* __restrict__ bk,
                                               const unsigned short* __restrict__ Wv,
                                               const float* __restrict__ bv,
                                               unsigned short* __restrict__ K16,
                                               unsigned short* __restrict__ V16)
{
    __shared__ __align__(16) char smem[64*72*2*3];   // 27,648 B
    unsigned short* sA  = (unsigned short*)smem;
    unsigned short* sBk = sA + 64*72;
    unsigned short* sBv = sA + 2*64*72;
    float* ep = (float*)smem;                        // [64n][65o]

    const int tid = threadIdx.x;
    const int lane = tid & 63, w = tid >> 6;
    const int l15 = lane & 15, lq = lane >> 4;
    const int n0 = blockIdx.x * 64, o0 = blockIdx.y * 64, b = blockIdx.z;
    const int qn = (w & 1) * 32, qo = (w >> 1) * 32;

    const unsigned short* xg = XT + ((size_t)b*N + n0)*C;
    const unsigned short* wkg = Wk + (size_t)o0*C;
    const unsigned short* wvg = Wv + (size_t)o0*C;

    const f32x4 zero = {0.f, 0.f, 0.f, 0.f};
    f32x4 k00 = zero, k01 = zero, k10 = zero, k11 = zero;
    f32x4 v00 = zero, v01 = zero, v10 = zero, v11 = zero;

    const int r = tid >> 2, c8 = (tid & 3) * 8;
    for (int c0 = 0; c0 < C; c0 += 64) {
        __syncthreads();
        *(bf16x8*)(sA  + r*72 + c8)      = *(const bf16x8*)(xg  + (size_t)r*C + c0 + c8);
        *(bf16x8*)(sA  + r*72 + c8 + 32) = *(const bf16x8*)(xg  + (size_t)r*C + c0 + c8 + 32);
        *(bf16x8*)(sBk + r*72 + c8)      = *(const bf16x8*)(wkg + (size_t)r*C + c0 + c8);
        *(bf16x8*)(sBk + r*72 + c8 + 32) = *(const bf16x8*)(wkg + (size_t)r*C + c0 + c8 + 32);
        *(bf16x8*)(sBv + r*72 + c8)      = *(const bf16x8*)(wvg + (size_t)r*C + c0 + c8);
        *(bf16x8*)(sBv + r*72 + c8 + 32) = *(const bf16x8*)(wvg + (size_t)r*C + c0 + c8 + 32);
        __syncthreads();
        #pragma unroll
        for (int ks = 0; ks < 2; ++ks) {
            bf16x8 fa0 = *(const bf16x8*)(sA + (qn + l15)*72      + ks*32 + lq*8);
            bf16x8 fa1 = *(const bf16x8*)(sA + (qn + 16 + l15)*72 + ks*32 + lq*8);
            bf16x8 fk0 = *(const bf16x8*)(sBk + (qo + l15)*72      + ks*32 + lq*8);
            bf16x8 fk1 = *(const bf16x8*)(sBk + (qo + 16 + l15)*72 + ks*32 + lq*8);
            bf16x8 fv0 = *(const bf16x8*)(sBv + (qo + l15)*72      + ks*32 + lq*8);
            bf16x8 fv1 = *(const bf16x8*)(sBv + (qo + 16 + l15)*72 + ks*32 + lq*8);
            k00 = __builtin_amdgcn_mfma_f32_16x16x32_bf16(fa0, fk0, k00, 0, 0, 0);
            k01 = __builtin_amdgcn_mfma_f32_16x16x32_bf16(fa0, fk1, k01, 0, 0, 0);
            k10 = __builtin_amdgcn_mfma_f32_16x16x32_bf16(fa1, fk0, k10, 0, 0, 0);
            k11 = __builtin_amdgcn_mfma_f32_16x16x32_bf16(fa1, fk1, k11, 0, 0, 0);
            v00 = __builtin_amdgcn_mfma_f32_16x16x32_bf16(fa0, fv0, v00, 0, 0, 0);
            v01 = __builtin_amdgcn_mfma_f32_16x16x32_bf16(fa0, fv1, v01, 0, 0, 0);
            v10 = __builtin_amdgcn_mfma_f32_16x16x32_bf16(fa1, fv0, v10, 0, 0, 0);
            v11 = __builtin_amdgcn_mfma_f32_16x16x32_bf16(fa1, fv1, v11, 0, 0, 0);
        }
    }
    // ---- K epilogue (token-major bf16, *SCALE) ----
    __syncthreads();
    #pragma unroll
    for (int rr = 0; rr < 4; ++rr) {
        int nr0 = qn + 4*lq + rr, nr1 = qn + 16 + 4*lq + rr;
        ep[nr0*65 + qo + l15]      = k00[rr];
        ep[nr0*65 + qo + 16 + l15] = k01[rr];
        ep[nr1*65 + qo + l15]      = k10[rr];
        ep[nr1*65 + qo + 16 + l15] = k11[rr];
    }
    __syncthreads();
    {
        int n = tid >> 2, ch = tid & 3;
        unsigned short* op = K16 + ((size_t)b*N + n0 + n)*C + o0;
        #pragma unroll
        for (int half = 0; half < 2; ++half) {
            int ob = ch*8 + half*32;
            bf16x8 v;
            #pragma unroll
            for (int j = 0; j < 8; ++j)
                v[j] = (short)bf16_bits((ep[n*65 + ob + j] + bk[o0 + ob + j]) * SCALE);
            *(bf16x8*)(op + ob) = v;
        }
    }
    // ---- V epilogue (spatial bf16) ----
    __syncthreads();
    #pragma unroll
    for (int rr = 0; rr < 4; ++rr) {
        int nr0 = qn + 4*lq + rr, nr1 = qn + 16 + 4*lq + rr;
        ep[nr0*65 + qo + l15]      = v00[rr];
        ep[nr0*65 + qo + 16 + l15] = v01[rr];
        ep[nr1*65 + qo + l15]      = v10[rr];
        ep[nr1*65 + qo + 16 + l15] = v11[rr];
    }
    __syncthreads();
    {
        int o = tid >> 2, nc = (tid & 3) * 16;
        float bz = bv[o0 + o];
        unsigned short* op = V16 + ((size_t)b*C + o0 + o)*N + n0 + nc;
        #pragma unroll
        for (int half = 0; half < 2; ++half) {
            bf16x8 v;
            #pragma unroll
            for (int j = 0; j < 8; ++j)
                v[j] = (short)bf16_bits(ep[(nc + half*8 + j)*65 + o] + bz);
            *(bf16x8*)(op + half*8) = v;
        }
    }
}

// ---------------------------------------------------------------------------
// Depthwise 5x5 conv (SAME, zero-pad) + bias + tanh GELU, halo-tiled in LDS.
// bf16 in, bf16 out. grid (4, 128, 24)
// ---------------------------------------------------------------------------
__global__ __launch_bounds__(256) void dwconv_gelu(const unsigned short* __restrict__ q,
                                                   const float* __restrict__ wdw,
                                                   const float* __restrict__ bdw,
                                                   unsigned short* __restrict__ t)
{
    __shared__ float tile[12][32];
    __shared__ float wsm[25];
    const int bx = blockIdx.x;           // 0..3 (8-row stripes)
    const int c = blockIdx.y, bg = blockIdx.z;
    const int tid = threadIdx.x;
    const unsigned short* qc = q + ((size_t)bg*Cg + c)*N;
    if (tid < 384) {
        int row = tid >> 5, col = tid & 31;
        int gy = bx*8 - 2 + row;
        tile[row][col] = (gy >= 0 && gy < H) ? bf2f(qc[gy*W + col]) : 0.0f;
    }
    if (tid < 25) wsm[tid] = wdw[c*25 + tid];
    __syncthreads();
    const int yl = tid >> 5, x = tid & 31;
    float acc = bdw[c];
    #pragma unroll
    for (int ky = 0; ky < 5; ++ky) {
        #pragma unroll
        for (int kx = 0; kx < 5; ++kx) {
            int xx = x + kx - 2;
            if (xx < 0 || xx >= W) continue;
            acc += wsm[ky*5 + kx] * tile[yl + ky][xx];
        }
    }
    float u = acc;
    float g = 0.5f*u*(1.0f + fast_tanh(0.7978845608028654f*(u + 0.044715f*u*u*u)));
    t[((size_t)bg*Cg + c)*N + bx*256 + tid] = bf16_bits(g);
}

// ---------------------------------------------------------------------------
// Merged: pointwise conv(2) + tanh + grid + bilinear gather -> sampT bf16.
// Reads bf16 tbuf. grid (16, 24)
// ---------------------------------------------------------------------------
__global__ __launch_bounds__(256) void offbilin(const unsigned short* __restrict__ t,
                                                const float* __restrict__ wpw,
                                                const float* __restrict__ bpw,
                                                const float* __restrict__ x2,
                                                unsigned short* __restrict__ sampT)
{
    __shared__ float r0[4][64], r1[4][64];
    __shared__ float4 cbuf[64];
    __shared__ unsigned short st[64][130];
    const int tid = threadIdx.x;
    const int n0 = blockIdx.x * 64, bg = blockIdx.y;
    const int nl = tid & 63, cq = tid >> 6;
    {
        const unsigned short* tb = t + ((size_t)bg*Cg + cq*32)*N + n0 + nl;
        float a0 = 0.f, a1 = 0.f;
        #pragma unroll 8
        for (int i = 0; i < 32; ++i) {
            float tv = bf2f(tb[(size_t)i*N]);
            a0 += wpw[cq*32 + i] * tv;
            a1 += wpw[Cg + cq*32 + i] * tv;
        }
        r0[cq][nl] = a0; r1[cq][nl] = a1;
    }
    __syncthreads();
    if (tid < 64) {
        int n = n0 + nl;
        const int x = n & 31, y = n >> 5;
        float a0 = bpw[0] + r0[0][nl] + r0[1][nl] + r0[2][nl] + r0[3][nl];
        float a1 = bpw[1] + r1[0][nl] + r1[1][nl] + r1[2][nl] + r1[3][nl];
        float dx = fast_tanh(a0) * (2.0f / W);
        float dy = fast_tanh(a1) * (2.0f / H);
        float rx = (x + 0.5f) / W * 2.0f - 1.0f;
        float ry = (y + 0.5f) / H * 2.0f - 1.0f;
        float px = fminf(fmaxf(rx + dx, -1.0f), 1.0f);
        float py = fminf(fmaxf(ry + dy, -1.0f), 1.0f);
        float gx = (px + 1.0f) * 0.5f * (W - 1);
        float gy = (py + 1.0f) * 0.5f * (H - 1);
        float x0 = floorf(gx), y0 = floorf(gy);
        float wx1 = gx - x0, wy1 = gy - y0;
        x0 = fminf(fmaxf(x0, 0.0f), (float)(W - 1));
        y0 = fminf(fmaxf(y0, 0.0f), (float)(H - 1));
        cbuf[nl] = make_float4(x0, y0, wx1, wy1);
    }
    __syncthreads();
    {
        float4 c4 = cbuf[nl];
        int x0 = (int)c4.x, y0 = (int)c4.y;
        float wx1 = c4.z, wy1 = c4.w;
        int x1 = min(x0 + 1, W - 1), y1 = min(y0 + 1, H - 1);
        float wx0 = 1.0f - wx1, wy0 = 1.0f - wy1;
        const float* base = x2 + (size_t)bg*Cg*N;
        #pragma unroll 4
        for (int i = 0; i < 32; ++i) {
            int c = cq*32 + i;
            const float* img = base + (size_t)c*N;
            float v00 = img[y0*W + x0], v01 = img[y0*W + x1];
            float v10 = img[y1*W + x0], v11 = img[y1*W + x1];
            float v = wy0*(wx0*v00 + wx1*v01) + wy1*(wx0*v10 + wx1*v11);
            st[nl][c] = bf16_bits(v);
        }
    }
    __syncthreads();
    {
        int b = bg / 3, g = bg % 3;
        int nn = tid >> 2;
        unsigned short* dp = sampT + ((size_t)b*N + n0 + nn)*C + g*Cg;
        #pragma unroll
        for (int i = 0; i < 4; ++i) {
            int c8 = ((tid & 3) + 4*i) * 8;
            *(bf16x8*)(dp + c8) = *(const bf16x8*)&st[nn][c8];
        }
    }
}

// ---------------------------------------------------------------------------
// Fused attention (R12-exact): 2-pass, LDS-staged K/V, transposed
// row-contiguous NT attn stores, __expf. LDS 46.6KB -> 3 blocks/CU.
// grid (1536), XCD-chunked swizzle.
// ---------------------------------------------------------------------------
__global__ __launch_bounds__(256) void attn_fused(const unsigned short* __restrict__ Q16,
                                                  const unsigned short* __restrict__ K16,
                                                  const unsigned short* __restrict__ V16,
                                                  float* __restrict__ attn,
                                                  unsigned short* __restrict__ OT)
{
    __shared__ __align__(16) unsigned short ks[256*40];    // 20,480 B
    __shared__ __align__(16) unsigned short vs[32*264];    // 16,896 B
    __shared__ __align__(16) unsigned short ps[4][16*72];  //  9,216 B

    const int tid = threadIdx.x;
    const int lane = tid & 63, w = tid >> 6;
    const int l15 = lane & 15, lq = lane >> 4;
    const int id = blockIdx.x;
    const int xcd = id & 7, j = id >> 3;
    const int bh = xcd*12 + (j >> 4);
    const int nb = j & 15;
    const int b = bh / HEADS, h = bh - b*HEADS;

    const unsigned short* qg = Q16 + ((size_t)b*N + nb*64)*C + h*32;
    const unsigned short* kg = K16 + (size_t)b*N*C + h*32;
    const unsigned short* vg = V16 + ((size_t)b*C + h*32)*N;

    const bf16x8 qfrag = *(const bf16x8*)(qg + (size_t)(w*16 + l15)*C + lq*8);

    const f32x4 zero = {0.f, 0.f, 0.f, 0.f};
    float sm = 0.f;
    f32x4 s[16];

    // ---------------- PASS 1: row sums only ----------------
    for (int ch = 0; ch < 4; ++ch) {
        __syncthreads();
        #pragma unroll
        for (int i = 0; i < 4; ++i) {
            int m = i*64 + (tid >> 2), c8 = (tid & 3) * 8;
            *(bf16x8*)(ks + m*40 + c8) = *(const bf16x8*)(kg + ((size_t)ch*256 + m)*C + c8);
        }
        __syncthreads();
        #pragma unroll
        for (int t = 0; t < 16; ++t) {
            bf16x8 kfrag = *(const bf16x8*)(ks + (16*t + l15)*40 + lq*8);
            s[t] = __builtin_amdgcn_mfma_f32_16x16x32_bf16(kfrag, qfrag, zero, 0, 0, 0);
        }
        float es = 0.f;
        #pragma unroll
        for (int t = 0; t < 16; ++t) {
            es += __expf(s[t][0]); es += __expf(s[t][1]);
            es += __expf(s[t][2]); es += __expf(s[t][3]);
        }
        sm += es;
    }
    sm += __shfl_xor(sm, 16);
    sm += __shfl_xor(sm, 32);
    const float inv = 1.0f / sm;

    // ---------------- PASS 2: recompute + P write + PV ----------------
    f32x4 outf[2] = {zero, zero};
    unsigned short* pw = ps[w];
    float* abase = attn + ((size_t)bh*N + (size_t)nb*64 + w*16)*N;
    const int trow = lane >> 4;
    const int tcol = (lane & 15) * 4;

    for (int ch = 0; ch < 4; ++ch) {
        __syncthreads();
        #pragma unroll
        for (int i = 0; i < 4; ++i) {
            int m = i*64 + (tid >> 2), c8 = (tid & 3) * 8;
            *(bf16x8*)(ks + m*40 + c8) = *(const bf16x8*)(kg + ((size_t)ch*256 + m)*C + c8);
        }
        #pragma unroll
        for (int i = 0; i < 4; ++i) {
            int u = tid + i*256;
            int cl = u >> 5, gg = u & 31;
            *(bf16x8*)(vs + cl*264 + gg*8) = *(const bf16x8*)(vg + (size_t)cl*N + ch*256 + gg*8);
        }
        __syncthreads();
        #pragma unroll
        for (int t = 0; t < 16; ++t) {
            bf16x8 kfrag = *(const bf16x8*)(ks + (16*t + l15)*40 + lq*8);
            s[t] = __builtin_amdgcn_mfma_f32_16x16x32_bf16(kfrag, qfrag, zero, 0, 0, 0);
        }
        #pragma unroll
        for (int qr = 0; qr < 4; ++qr) {
            #pragma unroll
            for (int tt = 0; tt < 4; ++tt) {
                int t = qr*4 + tt;
                float e0 = __expf(s[t][0]), e1 = __expf(s[t][1]);
                float e2 = __expf(s[t][2]), e3 = __expf(s[t][3]);
                uint2 pb;
                pb.x = (unsigned)bf16_bits(e0) | ((unsigned)bf16_bits(e1) << 16);
                pb.y = (unsigned)bf16_bits(e2) | ((unsigned)bf16_bits(e3) << 16);
                *(uint2*)(pw + l15*72 + 16*tt + 4*lq) = pb;
            }
            __asm volatile("" ::: "memory");
            #pragma unroll
            for (int kk = 0; kk < 2; ++kk) {
                bf16x8 pa = *(const bf16x8*)(pw + l15*72 + kk*32 + lq*8);
                #pragma unroll
                for (int ct = 0; ct < 2; ++ct) {
                    bf16x8 vb = *(const bf16x8*)(vs + (16*ct + l15)*264 + qr*64 + kk*32 + lq*8);
                    outf[ct] = __builtin_amdgcn_mfma_f32_16x16x32_bf16(pa, vb, outf[ct], 0, 0, 0);
                }
            }
            #pragma unroll
            for (int it = 0; it < 4; ++it) {
                int row = it*4 + trow;
                uint2 u = *(const uint2*)(pw + row*72 + tcol);
                float invr = __shfl(inv, row);
                f32x4 p;
                p[0] = __builtin_bit_cast(float, u.x << 16) * invr;
                p[1] = __builtin_bit_cast(float, u.x & 0xffff0000u) * invr;
                p[2] = __builtin_bit_cast(float, u.y << 16) * invr;
                p[3] = __builtin_bit_cast(float, u.y & 0xffff0000u) * invr;
                __builtin_nontemporal_store(p,
                    (f32x4*)(abase + (size_t)row*N + ch*256 + qr*64 + tcol));
            }
            __asm volatile("" ::: "memory");
        }
    }

    // epilogue: fold inv (per output row n = 4lq+r) into PV result
    float* sc = (float*)pw;   // [16n][33c]
    #pragma unroll
    for (int r = 0; r < 4; ++r) {
        float invr = __shfl(inv, 4*lq + r);
        sc[(4*lq + r)*33 + l15]      = outf[0][r] * invr;
        sc[(4*lq + r)*33 + 16 + l15] = outf[1][r] * invr;
    }
    __asm volatile("" ::: "memory");
    {
        int n = lane >> 2, c8 = (lane & 3) * 8;
        bf16x8 v;
        #pragma unroll
        for (int j2 = 0; j2 < 8; ++j2)
            v[j2] = (short)bf16_bits(sc[n*33 + c8 + j2]);
        *(bf16x8*)(OT + ((size_t)b*N + nb*64 + w*16 + n)*C + h*32 + c8) = v;
    }
}

// ---------------------------------------------------------------------------
extern "C" void kernel_launch(void* const* d_in, const int* in_sizes, int n_in,
                              void* d_out, int out_size, void* d_ws, size_t ws_size,
                              hipStream_t stream)
{
    const float* x1  = (const float*)d_in[0];
    const float* x2  = (const float*)d_in[1];
    const float* wq  = (const float*)d_in[2];
    const float* bq  = (const float*)d_in[3];
    const float* wdw = (const float*)d_in[4];
    const float* bdw = (const float*)d_in[5];
    const float* wpw = (const float*)d_in[6];
    const float* bpw = (const float*)d_in[7];
    const float* wk  = (const float*)d_in[8];
    const float* bk  = (const float*)d_in[9];
    const float* wv  = (const float*)d_in[10];
    const float* bv  = (const float*)d_in[11];
    const float* wo  = (const float*)d_in[12];
    const float* bo  = (const float*)d_in[13];

    const size_t P = (size_t)B * C * N;          // 3,145,728 floats
    float* ws = (float*)d_ws;
    unsigned short* Q16   = (unsigned short*)ws;             // P ushorts
    unsigned short* qspat = (unsigned short*)(ws + P/2);     // P ushorts (bf16 spatial)
    unsigned short* sampT = (unsigned short*)(ws + P);       // P ushorts
    unsigned short* K16   = (unsigned short*)(ws + 3*P/2);   // P ushorts
    unsigned short* V16   = (unsigned short*)(ws + 2*P);     // P ushorts
    unsigned short* x1T   = (unsigned short*)(ws + 5*P/2);   // P ushorts, reused as OT
    unsigned short* OT    = x1T;
    unsigned short* tbuf  = (unsigned short*)(ws + 3*P);     // P ushorts (bf16)
    unsigned short* w16   = (unsigned short*)(ws + 7*P/2);   // 4*147456 halves
    unsigned short* w16q = w16;
    unsigned short* w16k = w16 + 147456;
    unsigned short* w16v = w16 + 2*147456;
    unsigned short* w16o = w16 + 3*147456;

    float* ybuf = (float*)d_out;                 // (B,C,H,W)
    float* attn = (float*)d_out + P;             // (B,HEADS,N,N)

    prep<<<dim3(1056), 256, 0, stream>>>(wq, wk, wv, wo, x1, w16, x1T);
    proj_mfma<3><<<dim3(16, 6, 8), 256, 0, stream>>>(x1T, w16q, bq, nullptr, Q16, qspat);
    dwconv_gelu<<<dim3(4, Cg, BG), 256, 0, stream>>>(qspat, wdw, bdw, tbuf);
    offbilin<<<dim3(16, BG), 256, 0, stream>>>(tbuf, wpw, bpw, x2, sampT);
    proj_kv<<<dim3(16, 6, 8), 256, 0, stream>>>(sampT, w16k, bk, w16v, bv, K16, V16);
    attn_fused<<<dim3(1536), 256, 0, stream>>>(Q16, K16, V16, attn, OT);
    proj_mfma<2><<<dim3(16, 6, 8), 256, 0, stream>>>(OT, w16o, bo, x1, ybuf, nullptr);
}